// Round 13
// baseline (646.803 us; speedup 1.0000x reference)
//
#include <hip/hip_runtime.h>

// EGA multi-headed attention, MI355X/gfx950.
// Round 13: big-GEMM tile 128x128 -> 256x128 (32 MFMA/K-step/wave vs 16,
//           same 2-phase loop). Pair structure, flash path, stage2, numerics
//           all unchanged from r12.
// Dims fixed: B=8, L=S=2048, E=1024, H=16, G=64, Ek=Ev=64, KD=VD=1024.

typedef float f32x4 __attribute__((ext_vector_type(4)));
typedef _Float16 f16x8 __attribute__((ext_vector_type(8)));
typedef unsigned short u16;

#define DEV static __device__ __forceinline__

DEV u16 f2h(float x){
  _Float16 h = (_Float16)x;
  return __builtin_bit_cast(u16, h);
}
DEV float h2f(u16 u){
  return (float)__builtin_bit_cast(_Float16, u);
}
DEV void split1h(float x, u16 &h, u16 &l){
  h = f2h(x);
  l = f2h(x - h2f(h));
}
DEV unsigned pk2h(float a, float b){
  return (unsigned)f2h(a) | ((unsigned)f2h(b) << 16);
}

// async global->LDS, 16B per lane; dst is wave-uniform base (HW adds lane*16)
DEV void gload16(const u16* src, u16* dst_lds){
  __builtin_amdgcn_global_load_lds(
      (__attribute__((address_space(1))) void*)src,
      (__attribute__((address_space(3))) void*)dst_lds, 16, 0, 0);
}

// ---------------- mask dtype sniff + normalize to uchar ----------------
__global__ __launch_bounds__(256)
void mask_norm(const unsigned char* __restrict__ src, unsigned char* __restrict__ dst, int n)
{
  const unsigned* w = (const unsigned*)src;
  const int tid = threadIdx.x;
  int local = 0;
  for (int i = tid; i < n/4; i += 256){
    unsigned v = w[i];
    if (v == 0x3F800000u) local |= 2;
    else if (v > 1u)      local |= 1;
  }
  __shared__ int red[256];
  red[tid] = local;
  __syncthreads();
  for (int s = 128; s; s >>= 1){
    if (tid < s) red[tid] |= red[tid+s];
    __syncthreads();
  }
  const int r = red[0];
  const int mode = (r & 2) ? 2 : ((r & 1) ? 1 : 0);   // 2=f32, 1=u8, 0=i32
  for (int i = tid; i < n; i += 256){
    unsigned char v;
    if (mode == 1) v = src[i] ? 1 : 0;
    else           v = w[i]   ? 1 : 0;
    dst[i] = v;
  }
}

// ---------------- fp32 -> f16 hi plane (8 elems/thread) ----------------
__global__ __launch_bounds__(256)
void conv_hi(const float* __restrict__ x, u16* __restrict__ hi, int n8)
{
  const int i = blockIdx.x*256 + threadIdx.x;
  if (i >= n8) return;
  f32x4 a = ((const f32x4*)x)[2*i], b = ((const f32x4*)x)[2*i+1];
  uint4 uh;
  uh.x = pk2h(a[0], a[1]); uh.y = pk2h(a[2], a[3]);
  uh.z = pk2h(b[0], b[1]); uh.w = pk2h(b[2], b[3]);
  ((uint4*)hi)[i] = uh;
}

// ---------------- 5x 1024x1024 transpose, fp32 -> f16 hi plane (z selects) ----------------
__global__ __launch_bounds__(256)
void transpose_hi5(const float* __restrict__ s0, const float* __restrict__ s1,
                   const float* __restrict__ s2, const float* __restrict__ s3,
                   const float* __restrict__ s4,
                   u16* __restrict__ d0, u16* __restrict__ d1, u16* __restrict__ d2,
                   u16* __restrict__ d3, u16* __restrict__ d4)
{
  const int z = blockIdx.z;
  const float* Wsrc = z == 0 ? s0 : z == 1 ? s1 : z == 2 ? s2 : z == 3 ? s3 : s4;
  u16* Whi = z == 0 ? d0 : z == 1 ? d1 : z == 2 ? d2 : z == 3 ? d3 : d4;
  __shared__ float t[64][65];
  const int tid = threadIdx.x;
  const int n0 = blockIdx.x * 64, k0 = blockIdx.y * 64;
  #pragma unroll
  for (int it = 0; it < 16; ++it){
    int e = it*256 + tid, r = e >> 6, c = e & 63;
    t[r][c] = Wsrc[(long)(k0+r)*1024 + (n0+c)];
  }
  __syncthreads();
  #pragma unroll
  for (int it = 0; it < 16; ++it){
    int e = it*256 + tid, r = e >> 6, c = e & 63;
    Whi[(long)(n0+r)*1024 + (k0+c)] = f2h(t[c][r]);
  }
}

// ---------------- f16 MFMA GEMM, global_load_lds staging, dbuf (r8 loop) ----------------
template<int TM, int TERMS, int CM, int EPI, int SWZ>
__global__ __launch_bounds__(256)
void gemm_g(const u16* __restrict__ Ah_g, const u16* __restrict__ Al_g,
            const u16* __restrict__ Bh_g,
            void* __restrict__ Cp, void* __restrict__ Cp2,
            const unsigned char* __restrict__ maskp,
            int K, int lda, int ldb, int ldc,
            long aB, long aH, long bB, long bH, long cB, long cH,
            int H2, int Ssz, float scale)
{
  constexpr int BN = 128, BK = 32;
  constexpr int WM = TM/2, WN = BN/2;
  constexpr int FM = WM/16, FN = WN/16;
  __shared__ __align__(16) u16 AhS[2][TM*BK];
  __shared__ __align__(16) u16 AlS[2][TERMS == 2 ? TM*BK : 8];
  __shared__ __align__(16) u16 BhS[2][BN*BK];

  const int tid = threadIdx.x;
  int bx = blockIdx.x, by = blockIdx.y;
  if constexpr (SWZ){
    const int gx = gridDim.x;
    const int nwg = gx * gridDim.y;
    const int q = nwg >> 3;
    const int flat = bx + gx * by;
    const int nf = (flat & 7) * q + (flat >> 3);
    bx = nf % gx; by = nf / gx;
  }
  const int batch = blockIdx.z;
  const int b = batch / H2, h = batch - b*H2;
  const long aOff = (long)b*aB + (long)h*aH;
  const long bOff = (long)b*bB + (long)h*bH;
  const long cOff = (long)b*cB + (long)h*cH;
  const int nBase = bx * BN;
  const int mBase = by * TM;
  const int wave = tid >> 6, lane = tid & 63;
  const int wm = wave >> 1, wn = wave & 1;
  const int cg8 = (lane & 3) * 8;
  const int rsub = lane >> 2;

  auto stage = [&](int buf, int k0){
    #pragma unroll
    for (int c = 0; c < TM/64; ++c){
      const int chunk = wave*(TM/64) + c;
      const long g = aOff + (long)(mBase + chunk*16 + rsub)*lda + k0 + cg8;
      gload16(Ah_g + g, &AhS[buf][chunk*512]);
      if constexpr (TERMS == 2) gload16(Al_g + g, &AlS[buf][chunk*512]);
    }
    #pragma unroll
    for (int c = 0; c < 2; ++c){
      const int chunk = wave*2 + c;
      const long g = bOff + (long)(nBase + chunk*16 + rsub)*ldb + k0 + cg8;
      gload16(Bh_g + g, &BhS[buf][chunk*512]);
    }
  };

  f32x4 acc[FM][FN] = {};

  stage(0, 0);
  __syncthreads();
  const int nk = K >> 5;
  for (int t = 0; t < nk; ++t){
    const int buf = t & 1;
    if (t + 1 < nk) stage(buf ^ 1, (t + 1) << 5);

    f16x8 ah[FM], al[FM], bh[FN];
    #pragma unroll
    for (int mi = 0; mi < FM; ++mi){
      const int off = (wm*WM + mi*16 + (lane & 15))*BK + (lane >> 4)*8;
      ah[mi] = *(const f16x8*)&AhS[buf][off];
      if constexpr (TERMS == 2) al[mi] = *(const f16x8*)&AlS[buf][off];
    }
    #pragma unroll
    for (int ni = 0; ni < FN; ++ni){
      const int off = (wn*WN + ni*16 + (lane & 15))*BK + (lane >> 4)*8;
      bh[ni] = *(const f16x8*)&BhS[buf][off];
    }
    #pragma unroll
    for (int mi = 0; mi < FM; ++mi)
      #pragma unroll
      for (int ni = 0; ni < FN; ++ni){
        acc[mi][ni] = __builtin_amdgcn_mfma_f32_16x16x32_f16(ah[mi], bh[ni], acc[mi][ni], 0, 0, 0);
        if constexpr (TERMS == 2)
          acc[mi][ni] = __builtin_amdgcn_mfma_f32_16x16x32_f16(al[mi], bh[ni], acc[mi][ni], 0, 0, 0);
      }
    __syncthreads();
  }

  const int cr = (lane >> 4) * 4, cc = lane & 15;
  #pragma unroll
  for (int mi = 0; mi < FM; ++mi)
    #pragma unroll
    for (int ni = 0; ni < FN; ++ni)
      #pragma unroll
      for (int r = 0; r < 4; ++r){
        const int row = mBase + wm*WM + mi*16 + cr + r;
        const int col = nBase + wn*WN + ni*16 + cc;
        float v = acc[mi][ni][r];
        if constexpr (EPI == 1){
          v *= scale;
          if (maskp[(long)b*Ssz + col]) v = -50000.0f;
        }
        const long ci = cOff + (long)row*ldc + col;
        if constexpr (CM == 0){
          ((float*)Cp)[ci] = v;
        } else {
          u16 hh, ll;
          split1h(v, hh, ll);
          ((u16*)Cp)[ci]  = hh;
          ((u16*)Cp2)[ci] = ll;
        }
      }
}

// ---------------- merged dual-GEMM dispatch (1-term A, planes out) ----------------
struct PArg {
  const void* Ap;        // u16 plane (AMODE=1) or f32 (AMODE=0)
  const u16*  Bh;
  u16* Ch; u16* Cl;
  long bB, cB;           // z strides for B and C (A has none)
  int lda, ldb, ldc;
  int nbx, nby;
};

template<int TM, int AMODE>
__global__ __launch_bounds__(256)
void gemm_pair(PArg a0, PArg a1, int n0, int K)
{
  constexpr int BN = 128, BK = 32;
  constexpr int WM = TM/2, WN = BN/2;
  constexpr int FM = WM/16, FN = WN/16;
  constexpr int NC = TM/64;                 // A chunks per thread
  __shared__ __align__(16) u16 AhS[2][TM*BK];
  __shared__ __align__(16) u16 BhS[2][BN*BK];

  const int tid = threadIdx.x;
  const int gid = blockIdx.x;
  const PArg P = (gid < n0) ? a0 : a1;
  int lid = (gid < n0) ? gid : gid - n0;
  const int gsz = (gid < n0) ? n0 : ((int)gridDim.x - n0);
  {
    const int q = gsz >> 3;
    lid = (lid & 7) * q + (lid >> 3);
  }
  const int bx = lid % P.nbx;
  const int rest = lid / P.nbx;
  const int by = rest % P.nby;
  const int z  = rest / P.nby;
  const long bOff = (long)z * P.bB;
  const long cOff = (long)z * P.cB;
  const int nBase = bx * BN;
  const int mBase = by * TM;
  const int wave = tid >> 6, lane = tid & 63;
  const int wm = wave >> 1, wn = wave & 1;
  const int cg8 = (lane & 3) * 8;
  const int rsub = lane >> 2;

  const u16* Au = (const u16*)P.Ap;
  const float* Af = (const float*)P.Ap;

  auto stageB = [&](int buf, int k0){
    #pragma unroll
    for (int c = 0; c < 2; ++c){
      const int chunk = wave*2 + c;
      const long g = bOff + (long)(nBase + chunk*16 + rsub)*P.ldb + k0 + cg8;
      gload16(P.Bh + g, &BhS[buf][chunk*512]);
    }
  };
  auto stageA_g = [&](int buf, int k0){
    #pragma unroll
    for (int c = 0; c < NC; ++c){
      const int chunk = wave*NC + c;
      const long g = (long)(mBase + chunk*16 + rsub)*P.lda + k0 + cg8;
      gload16(Au + g, &AhS[buf][chunk*512]);
    }
  };

  f32x4 acc[FM][FN] = {};
  f32x4 sA0[NC], sA1[NC];

  auto loadA_f = [&](int k0){
    #pragma unroll
    for (int c = 0; c < NC; ++c){
      const int chunk = wave*NC + c;
      const long g = (long)(mBase + chunk*16 + rsub)*P.lda + k0 + cg8;
      sA0[c] = *(const f32x4*)(Af + g);
      sA1[c] = *(const f32x4*)(Af + g + 4);
    }
  };
  auto writeA_f = [&](int buf){
    #pragma unroll
    for (int c = 0; c < NC; ++c){
      const int chunk = wave*NC + c;
      uint4 u;
      u.x = pk2h(sA0[c][0], sA0[c][1]); u.y = pk2h(sA0[c][2], sA0[c][3]);
      u.z = pk2h(sA1[c][0], sA1[c][1]); u.w = pk2h(sA1[c][2], sA1[c][3]);
      *(uint4*)&AhS[buf][chunk*512 + (long)lane*8] = u;
    }
  };

  stageB(0, 0);
  if constexpr (AMODE == 1) stageA_g(0, 0);
  else { loadA_f(0); writeA_f(0); }
  __syncthreads();

  const int nk = K >> 5;
  for (int t = 0; t < nk; ++t){
    const int buf = t & 1;
    if (t + 1 < nk){
      stageB(buf ^ 1, (t + 1) << 5);
      if constexpr (AMODE == 1) stageA_g(buf ^ 1, (t + 1) << 5);
      else loadA_f((t + 1) << 5);
    }

    f16x8 ah[FM], bh[FN];
    #pragma unroll
    for (int mi = 0; mi < FM; ++mi){
      const int off = (wm*WM + mi*16 + (lane & 15))*BK + (lane >> 4)*8;
      ah[mi] = *(const f16x8*)&AhS[buf][off];
    }
    #pragma unroll
    for (int ni = 0; ni < FN; ++ni){
      const int off = (wn*WN + ni*16 + (lane & 15))*BK + (lane >> 4)*8;
      bh[ni] = *(const f16x8*)&BhS[buf][off];
    }
    #pragma unroll
    for (int mi = 0; mi < FM; ++mi)
      #pragma unroll
      for (int ni = 0; ni < FN; ++ni)
        acc[mi][ni] = __builtin_amdgcn_mfma_f32_16x16x32_f16(ah[mi], bh[ni], acc[mi][ni], 0, 0, 0);

    if constexpr (AMODE == 0){
      if (t + 1 < nk) writeA_f(buf ^ 1);
    }
    __syncthreads();
  }

  const int cr = (lane >> 4) * 4, cc = lane & 15;
  #pragma unroll
  for (int mi = 0; mi < FM; ++mi)
    #pragma unroll
    for (int ni = 0; ni < FN; ++ni)
      #pragma unroll
      for (int r = 0; r < 4; ++r){
        const int row = mBase + wm*WM + mi*16 + cr + r;
        const int col = nBase + wn*WN + ni*16 + cc;
        const long ci = cOff + (long)row*P.ldc + col;
        u16 hh, ll;
        split1h(acc[mi][ni][r], hh, ll);
        P.Ch[ci] = hh;
        P.Cl[ci] = ll;
      }
}

// ---------------- flash aggregation v2 (unchanged) ----------------
template<int NB>
__global__ __launch_bounds__(256)
void flash_agg(const u16* __restrict__ Sh_g, const u16* __restrict__ Sl_g,
               const u16* __restrict__ B1h_g, const u16* __restrict__ B1l_g,
               const u16* __restrict__ B2h_g, const u16* __restrict__ B2l_g,
               float* __restrict__ P1, float* __restrict__ P2,
               float* __restrict__ msm, float* __restrict__ mss,
               int K, int KC, int lda, int ldb,
               long aB, long aH, long bB, long bH, int H2, int nbatch)
{
  __shared__ __align__(16) u16 Ph[64][72], Pl[64][72];
  __shared__ __align__(16) u16 B1hS[64][72], B1lS[64][72];
  __shared__ __align__(16) u16 B2hS[NB==2?64:1][72], B2lS[NB==2?64:1][72];
  __shared__ float mS[64], sS[64], fS[64];
  const int tid = threadIdx.x;
  const int kc = blockIdx.x, batch = blockIdx.y;
  const int b = batch / H2, h = batch - b*H2;
  const long aOff = (long)b*aB + (long)h*aH;
  const long bOff = (long)b*bB + (long)h*bH;
  const int kchunk = K / KC, kbeg = kc * kchunk;
  const int wm = tid >> 6, lane = tid & 63;
  const int srow = tid >> 2, sq = tid & 3;

  if (tid < 64){ mS[tid] = -1e30f; sS[tid] = 0.f; }

  f32x4 acc1[4] = {}, acc2[4] = {};

  for (int ks = kbeg; ks < kbeg + kchunk; ks += 64){
    __syncthreads();
    #pragma unroll
    for (int it = 0; it < 4; ++it){
      const int e = it*256 + tid;
      const int lr = e >> 4, d0 = (e & 15) * 4;
      const long gm = bOff + (long)(ks + lr)*ldb + d0;
      ushort4 h4 = *(const ushort4*)(B1h_g + gm);
      ushort4 l4 = *(const ushort4*)(B1l_g + gm);
      B1hS[d0+0][lr]=h4.x; B1hS[d0+1][lr]=h4.y; B1hS[d0+2][lr]=h4.z; B1hS[d0+3][lr]=h4.w;
      B1lS[d0+0][lr]=l4.x; B1lS[d0+1][lr]=l4.y; B1lS[d0+2][lr]=l4.z; B1lS[d0+3][lr]=l4.w;
      if constexpr (NB == 2){
        ushort4 h42 = *(const ushort4*)(B2h_g + gm);
        ushort4 l42 = *(const ushort4*)(B2l_g + gm);
        B2hS[d0+0][lr]=h42.x; B2hS[d0+1][lr]=h42.y; B2hS[d0+2][lr]=h42.z; B2hS[d0+3][lr]=h42.w;
        B2lS[d0+0][lr]=l42.x; B2lS[d0+1][lr]=l42.y; B2lS[d0+2][lr]=l42.z; B2lS[d0+3][lr]=l42.w;
      }
    }

    float v[16];
    {
      const long ga = aOff + (long)srow*lda + ks + sq*16;
      uint4 ha = *(const uint4*)(Sh_g + ga);
      uint4 hb = *(const uint4*)(Sh_g + ga + 8);
      uint4 la = *(const uint4*)(Sl_g + ga);
      uint4 lb = *(const uint4*)(Sl_g + ga + 8);
      v[0]=h2f((u16)ha.x)+h2f((u16)la.x);  v[1]=h2f((u16)(ha.x>>16))+h2f((u16)(la.x>>16));
      v[2]=h2f((u16)ha.y)+h2f((u16)la.y);  v[3]=h2f((u16)(ha.y>>16))+h2f((u16)(la.y>>16));
      v[4]=h2f((u16)ha.z)+h2f((u16)la.z);  v[5]=h2f((u16)(ha.z>>16))+h2f((u16)(la.z>>16));
      v[6]=h2f((u16)ha.w)+h2f((u16)la.w);  v[7]=h2f((u16)(ha.w>>16))+h2f((u16)(la.w>>16));
      v[8]=h2f((u16)hb.x)+h2f((u16)lb.x);  v[9]=h2f((u16)(hb.x>>16))+h2f((u16)(lb.x>>16));
      v[10]=h2f((u16)hb.y)+h2f((u16)lb.y); v[11]=h2f((u16)(hb.y>>16))+h2f((u16)(lb.y>>16));
      v[12]=h2f((u16)hb.z)+h2f((u16)lb.z); v[13]=h2f((u16)(hb.z>>16))+h2f((u16)(lb.z>>16));
      v[14]=h2f((u16)hb.w)+h2f((u16)lb.w); v[15]=h2f((u16)(hb.w>>16))+h2f((u16)(lb.w>>16));
    }
    float mx = v[0];
    #pragma unroll
    for (int i = 1; i < 16; ++i) mx = fmaxf(mx, v[i]);
    mx = fmaxf(mx, __shfl_xor(mx, 1));
    mx = fmaxf(mx, __shfl_xor(mx, 2));
    const float mold = mS[srow];
    const float mnew = fmaxf(mold, mx);
    float sum = 0.f;
    u16 ph[16], pl[16];
    #pragma unroll
    for (int i = 0; i < 16; ++i){
      float e = __expf(v[i] - mnew);
      sum += e;
      split1h(e, ph[i], pl[i]);
    }
    sum += __shfl_xor(sum, 1);
    sum += __shfl_xor(sum, 2);
    if (sq == 0){
      const float f = __expf(mold - mnew);
      sS[srow] = sS[srow] * f + sum;
      mS[srow] = mnew;
      fS[srow] = f;
    }
    {
      uint4 uh0, uh1, ul0, ul1;
      uh0.x=(unsigned)ph[0]|((unsigned)ph[1]<<16);  uh0.y=(unsigned)ph[2]|((unsigned)ph[3]<<16);
      uh0.z=(unsigned)ph[4]|((unsigned)ph[5]<<16);  uh0.w=(unsigned)ph[6]|((unsigned)ph[7]<<16);
      uh1.x=(unsigned)ph[8]|((unsigned)ph[9]<<16);  uh1.y=(unsigned)ph[10]|((unsigned)ph[11]<<16);
      uh1.z=(unsigned)ph[12]|((unsigned)ph[13]<<16);uh1.w=(unsigned)ph[14]|((unsigned)ph[15]<<16);
      ul0.x=(unsigned)pl[0]|((unsigned)pl[1]<<16);  ul0.y=(unsigned)pl[2]|((unsigned)pl[3]<<16);
      ul0.z=(unsigned)pl[4]|((unsigned)pl[5]<<16);  ul0.w=(unsigned)pl[6]|((unsigned)pl[7]<<16);
      ul1.x=(unsigned)pl[8]|((unsigned)pl[9]<<16);  ul1.y=(unsigned)pl[10]|((unsigned)pl[11]<<16);
      ul1.z=(unsigned)pl[12]|((unsigned)pl[13]<<16);ul1.w=(unsigned)pl[14]|((unsigned)pl[15]<<16);
      *(uint4*)&Ph[srow][sq*16]     = uh0;
      *(uint4*)&Ph[srow][sq*16 + 8] = uh1;
      *(uint4*)&Pl[srow][sq*16]     = ul0;
      *(uint4*)&Pl[srow][sq*16 + 8] = ul1;
    }
    __syncthreads();

    float fr4[4];
    #pragma unroll
    for (int r = 0; r < 4; ++r) fr4[r] = fS[wm*16 + (lane >> 4)*4 + r];
    #pragma unroll
    for (int ni = 0; ni < 4; ++ni)
      #pragma unroll
      for (int r = 0; r < 4; ++r){
        acc1[ni][r] *= fr4[r];
        if constexpr (NB == 2) acc2[ni][r] *= fr4[r];
      }
    #pragma unroll
    for (int k0 = 0; k0 < 64; k0 += 32){
      const int ko = k0 + (lane >> 4)*8;
      const int fr = lane & 15;
      f16x8 a_h = *(const f16x8*)&Ph[wm*16 + fr][ko];
      f16x8 a_l = *(const f16x8*)&Pl[wm*16 + fr][ko];
      #pragma unroll
      for (int ni = 0; ni < 4; ++ni){
        f16x8 b_h = *(const f16x8*)&B1hS[ni*16 + fr][ko];
        f16x8 b_l = *(const f16x8*)&B1lS[ni*16 + fr][ko];
        acc1[ni] = __builtin_amdgcn_mfma_f32_16x16x32_f16(a_h, b_h, acc1[ni], 0, 0, 0);
        acc1[ni] = __builtin_amdgcn_mfma_f32_16x16x32_f16(a_l, b_h, acc1[ni], 0, 0, 0);
        acc1[ni] = __builtin_amdgcn_mfma_f32_16x16x32_f16(a_h, b_l, acc1[ni], 0, 0, 0);
        if constexpr (NB == 2){
          f16x8 c_h = *(const f16x8*)&B2hS[ni*16 + fr][ko];
          f16x8 c_l = *(const f16x8*)&B2lS[ni*16 + fr][ko];
          acc2[ni] = __builtin_amdgcn_mfma_f32_16x16x32_f16(a_h, c_h, acc2[ni], 0, 0, 0);
          acc2[ni] = __builtin_amdgcn_mfma_f32_16x16x32_f16(a_l, c_h, acc2[ni], 0, 0, 0);
          acc2[ni] = __builtin_amdgcn_mfma_f32_16x16x32_f16(a_h, c_l, acc2[ni], 0, 0, 0);
        }
      }
    }
  }

  const long po = ((long)(kc*nbatch + batch) << 12);
  const int cr = (lane >> 4) * 4, cc = lane & 15;
  #pragma unroll
  for (int ni = 0; ni < 4; ++ni)
    #pragma unroll
    for (int r = 0; r < 4; ++r){
      const int g = wm*16 + cr + r, d = ni*16 + cc;
      P1[po + g*64 + d] = acc1[ni][r];
      if constexpr (NB == 2) P2[po + g*64 + d] = acc2[ni][r];
    }
  if (tid < 64){
    msm[((long)kc*nbatch + batch)*64 + tid] = mS[tid];
    mss[((long)kc*nbatch + batch)*64 + tid] = sS[tid];
  }
}

// ---------------- exact cross-chunk combine (compile-time KC) ----------------
template<int NB, int KC>
__global__ __launch_bounds__(256)
void flash_combine(const float* __restrict__ P1, const float* __restrict__ P2,
                   const float* __restrict__ msm, const float* __restrict__ mss,
                   u16* __restrict__ o1h, u16* __restrict__ o1l,
                   u16* __restrict__ o2h, u16* __restrict__ o2l, int nbatch)
{
  const int batch = blockIdx.x;
  const int tid = threadIdx.x;
  const int g = tid >> 2, dq = (tid & 3) * 16;
  float m[KC], s[KC], w[KC];
  float M = -1e30f;
  #pragma unroll
  for (int c = 0; c < KC; ++c){
    m[c] = msm[((long)c*nbatch + batch)*64 + g];
    s[c] = mss[((long)c*nbatch + batch)*64 + g];
    M = fmaxf(M, m[c]);
  }
  float den = 0.f;
  #pragma unroll
  for (int c = 0; c < KC; ++c){ w[c] = __expf(m[c] - M); den += s[c]*w[c]; }
  const float inv = 1.0f / den;
  #pragma unroll
  for (int c = 0; c < KC; ++c) w[c] *= inv;
  const long oo = (long)batch*4096 + g*64 + dq;
  #pragma unroll
  for (int nb = 0; nb < NB; ++nb){
    const float* Pa = nb ? P2 : P1;
    u16* oh = nb ? o2h : o1h;
    u16* ol = nb ? o2l : o1l;
    u16 hh[16], ll[16];
    #pragma unroll
    for (int j = 0; j < 4; ++j){
      f32x4 a = {0.f, 0.f, 0.f, 0.f};
      #pragma unroll
      for (int c = 0; c < KC; ++c){
        f32x4 p = *(const f32x4*)(Pa + (((long)c*nbatch + batch) << 12) + g*64 + dq + j*4);
        a += p * w[c];
      }
      #pragma unroll
      for (int e = 0; e < 4; ++e) split1h(a[e], hh[j*4+e], ll[j*4+e]);
    }
    uint4 uh0, uh1, ul0, ul1;
    uh0.x=(unsigned)hh[0]|((unsigned)hh[1]<<16);  uh0.y=(unsigned)hh[2]|((unsigned)hh[3]<<16);
    uh0.z=(unsigned)hh[4]|((unsigned)hh[5]<<16);  uh0.w=(unsigned)hh[6]|((unsigned)hh[7]<<16);
    uh1.x=(unsigned)hh[8]|((unsigned)hh[9]<<16);  uh1.y=(unsigned)hh[10]|((unsigned)hh[11]<<16);
    uh1.z=(unsigned)hh[12]|((unsigned)hh[13]<<16);uh1.w=(unsigned)hh[14]|((unsigned)hh[15]<<16);
    ul0.x=(unsigned)ll[0]|((unsigned)ll[1]<<16);  ul0.y=(unsigned)ll[2]|((unsigned)ll[3]<<16);
    ul0.z=(unsigned)ll[4]|((unsigned)ll[5]<<16);  ul0.w=(unsigned)ll[6]|((unsigned)ll[7]<<16);
    ul1.x=(unsigned)ll[8]|((unsigned)ll[9]<<16);  ul1.y=(unsigned)ll[10]|((unsigned)ll[11]<<16);
    ul1.z=(unsigned)ll[12]|((unsigned)ll[13]<<16);ul1.w=(unsigned)ll[14]|((unsigned)ll[15]<<16);
    *(uint4*)(oh + oo)     = uh0;
    *(uint4*)(oh + oo + 8) = uh1;
    *(uint4*)(ol + oo)     = ul0;
    *(uint4*)(ol + oo + 8) = ul1;
  }
}

// ---------------- stage 2, MFMA (unchanged) ----------------
__global__ __launch_bounds__(256)
void stage2_mfma(const u16* __restrict__ qhi, const u16* __restrict__ qlo,
                 const u16* __restrict__ gkh_g, const u16* __restrict__ gkl_g,
                 const u16* __restrict__ gvh_g, const u16* __restrict__ gvl_g,
                 float* __restrict__ lattn, u16* __restrict__ ahi,
                 float scale)
{
  __shared__ __align__(16) u16 Ah[128][72];
  __shared__ __align__(16) u16 Al[128][72];
  __shared__ __align__(16) u16 Bh[64][72];
  __shared__ __align__(16) u16 Bl[64][72];
  const int tid = threadIdx.x;
  const int bh = blockIdx.y;
  const int b = bh >> 4, h = bh & 15;
  const int l0 = blockIdx.x * 128;
  const int wm = tid >> 6, lane = tid & 63;

  const long qbase = ((long)b*2048 + l0)*1024 + h*64;
  #pragma unroll
  for (int it = 0; it < 4; ++it){
    const int e = it*256 + tid, row = e >> 3, s = e & 7;
    const long g = qbase + (long)row*1024 + s*8;
    *(uint4*)&Ah[row][s*8] = *(const uint4*)(qhi + g);
    *(uint4*)&Al[row][s*8] = *(const uint4*)(qlo + g);
  }
  const long gb = (long)bh * 4096;
  #pragma unroll
  for (int it = 0; it < 2; ++it){
    const int e = it*256 + tid, gr = e >> 3, s = e & 7;
    *(uint4*)&Bh[gr][s*8] = *(const uint4*)(gkh_g + gb + gr*64 + s*8);
    *(uint4*)&Bl[gr][s*8] = *(const uint4*)(gkl_g + gb + gr*64 + s*8);
  }
  __syncthreads();

  f32x4 acc[2][4] = {};
  #pragma unroll
  for (int k0 = 0; k0 < 64; k0 += 32){
    f16x8 a_h[2], a_l[2], b_h[4], b_l[4];
    #pragma unroll
    for (int mi = 0; mi < 2; ++mi){
      const int row = wm*32 + mi*16 + (lane & 15);
      a_h[mi] = *(const f16x8*)&Ah[row][k0 + (lane >> 4)*8];
      a_l[mi] = *(const f16x8*)&Al[row][k0 + (lane >> 4)*8];
    }
    #pragma unroll
    for (int ni = 0; ni < 4; ++ni){
      const int nr = ni*16 + (lane & 15);
      b_h[ni] = *(const f16x8*)&Bh[nr][k0 + (lane >> 4)*8];
      b_l[ni] = *(const f16x8*)&Bl[nr][k0 + (lane >> 4)*8];
    }
    #pragma unroll
    for (int mi = 0; mi < 2; ++mi)
      #pragma unroll
      for (int ni = 0; ni < 4; ++ni){
        acc[mi][ni] = __builtin_amdgcn_mfma_f32_16x16x32_f16(a_h[mi], b_h[ni], acc[mi][ni], 0, 0, 0);
        acc[mi][ni] = __builtin_amdgcn_mfma_f32_16x16x32_f16(a_l[mi], b_h[ni], acc[mi][ni], 0, 0, 0);
        acc[mi][ni] = __builtin_amdgcn_mfma_f32_16x16x32_f16(a_h[mi], b_l[ni], acc[mi][ni], 0, 0, 0);
      }
  }
  __syncthreads();

  #pragma unroll
  for (int it = 0; it < 4; ++it){
    const int e = it*256 + tid;
    const int gr = e >> 4, d0 = (e & 15) * 4;
    ushort4 vh = *(const ushort4*)(gvh_g + gb + gr*64 + d0);
    ushort4 vl = *(const ushort4*)(gvl_g + gb + gr*64 + d0);
    Bh[d0+0][gr] = vh.x; Bh[d0+1][gr] = vh.y; Bh[d0+2][gr] = vh.z; Bh[d0+3][gr] = vh.w;
    Bl[d0+0][gr] = vl.x; Bl[d0+1][gr] = vl.y; Bl[d0+2][gr] = vl.z; Bl[d0+3][gr] = vl.w;
  }

  #pragma unroll
  for (int mi = 0; mi < 2; ++mi){
    #pragma unroll
    for (int r = 0; r < 4; ++r){
      float v0 = acc[mi][0][r]*scale, v1 = acc[mi][1][r]*scale;
      float v2 = acc[mi][2][r]*scale, v3 = acc[mi][3][r]*scale;
      float mx = fmaxf(fmaxf(v0,v1), fmaxf(v2,v3));
      #pragma unroll
      for (int off = 1; off < 16; off <<= 1) mx = fmaxf(mx, __shfl_xor(mx, off, 16));
      float e0 = __expf(v0-mx), e1 = __expf(v1-mx), e2 = __expf(v2-mx), e3 = __expf(v3-mx);
      float sum = (e0+e1) + (e2+e3);
      #pragma unroll
      for (int off = 1; off < 16; off <<= 1) sum += __shfl_xor(sum, off, 16);
      const float inv = 1.0f / sum;
      e0 *= inv; e1 *= inv; e2 *= inv; e3 *= inv;
      const int lrow = wm*32 + mi*16 + (lane >> 4)*4 + r;
      float* lp = lattn + ((long)bh*2048 + l0 + lrow)*64 + (lane & 15);
      lp[0] = e0; lp[16] = e1; lp[32] = e2; lp[48] = e3;
      u16 hh, ll;
      split1h(e0, hh, ll); Ah[lrow][ 0 + (lane&15)] = hh; Al[lrow][ 0 + (lane&15)] = ll;
      split1h(e1, hh, ll); Ah[lrow][16 + (lane&15)] = hh; Al[lrow][16 + (lane&15)] = ll;
      split1h(e2, hh, ll); Ah[lrow][32 + (lane&15)] = hh; Al[lrow][32 + (lane&15)] = ll;
      split1h(e3, hh, ll); Ah[lrow][48 + (lane&15)] = hh; Al[lrow][48 + (lane&15)] = ll;
    }
  }
  __syncthreads();

  f32x4 o[2][4] = {};
  #pragma unroll
  for (int k0 = 0; k0 < 64; k0 += 32){
    f16x8 p_h[2], p_l[2], b_h[4], b_l[4];
    #pragma unroll
    for (int mi = 0; mi < 2; ++mi){
      const int row = wm*32 + mi*16 + (lane & 15);
      p_h[mi] = *(const f16x8*)&Ah[row][k0 + (lane >> 4)*8];
      p_l[mi] = *(const f16x8*)&Al[row][k0 + (lane >> 4)*8];
    }
    #pragma unroll
    for (int ni = 0; ni < 4; ++ni){
      const int nr = ni*16 + (lane & 15);
      b_h[ni] = *(const f16x8*)&Bh[nr][k0 + (lane >> 4)*8];
      b_l[ni] = *(const f16x8*)&Bl[nr][k0 + (lane >> 4)*8];
    }
    #pragma unroll
    for (int mi = 0; mi < 2; ++mi)
      #pragma unroll
      for (int ni = 0; ni < 4; ++ni){
        o[mi][ni] = __builtin_amdgcn_mfma_f32_16x16x32_f16(p_h[mi], b_h[ni], o[mi][ni], 0, 0, 0);
        o[mi][ni] = __builtin_amdgcn_mfma_f32_16x16x32_f16(p_l[mi], b_h[ni], o[mi][ni], 0, 0, 0);
        o[mi][ni] = __builtin_amdgcn_mfma_f32_16x16x32_f16(p_h[mi], b_l[ni], o[mi][ni], 0, 0, 0);
      }
  }

  #pragma unroll
  for (int mi = 0; mi < 2; ++mi)
    #pragma unroll
    for (int ni = 0; ni < 4; ++ni)
      #pragma unroll
      for (int r = 0; r < 4; ++r){
        const int lrow = wm*32 + mi*16 + (lane >> 4)*4 + r;
        const int d = ni*16 + (lane & 15);
        const long oidx = ((long)b*2048 + l0 + lrow)*1024 + h*64 + d;
        ahi[oidx] = f2h(o[mi][ni][r]);
      }
}

extern "C" void kernel_launch(void* const* d_in, const int* in_sizes, int n_in,
                              void* d_out, int out_size, void* d_ws, size_t ws_size,
                              hipStream_t stream)
{
  const float* query = (const float*)d_in[0];
  const float* key   = (const float*)d_in[1];
  const float* value = (const float*)d_in[2];
  const unsigned char* mask_raw = (const unsigned char*)d_in[4];
  const float* Wq = (const float*)d_in[6];
  const float* Wk = (const float*)d_in[7];
  const float* Wv = (const float*)d_in[8];
  const float* Wi = (const float*)d_in[9];
  const float* Wo = (const float*)d_in[10];
  float* out0 = (float*)d_out;                  // (B,L,E)
  float* out1 = out0 + 16777216;                // (B,H,L,G)

  // ---- workspace map (MiB), liveness-checked (same as r12) ----
  char* ws = (char*)d_ws;
  u16* WoT_hi = (u16*)(ws + 0);
  float* msm_q = (float*)(ws + (2L<<20));
  float* mss_q = (float*)(ws + (2L<<20) + 262144);
  float* msm_g = (float*)(ws + (3L<<20));
  float* mss_g = (float*)(ws + (3L<<20) + 262144);
  u16* WqT_hi = (u16*)(ws + (4L<<20));
  unsigned char* mask_ws = (unsigned char*)(ws + (6L<<20));
  float* part1 = (float*)(ws + (4L<<20));
  u16* WkT_hi = (u16*)(ws + (8L<<20));
  u16* WvT_hi = (u16*)(ws + (12L<<20));
  float* part2 = (float*)(ws + (12L<<20));
  u16* gqs_hi = (u16*)(ws + (16L<<20));
  u16* gqs_lo = (u16*)(ws + (17L<<20));
  u16* WiT_hi = (u16*)(ws + (18L<<20));
  u16* qp_hi  = (u16*)(ws + (20L<<20));
  u16* gsc_hi = (u16*)(ws + (20L<<20));
  u16* gsc_lo = (u16*)(ws + (52L<<20));
  u16* qs_hi  = (u16*)(ws + (84L<<20));
  u16* qs_lo  = (u16*)(ws + (116L<<20));
  float* partg = (float*)(ws + (148L<<20));
  u16* vs_hi  = (u16*)(ws + (148L<<20));
  u16* vs_lo  = (u16*)(ws + (180L<<20));
  u16* ips_hi = (u16*)(ws + (212L<<20));
  u16* ips_lo = (u16*)(ws + (244L<<20));
  u16* kk_hi  = (u16*)(ws + (212L<<20));
  u16* kk_lo  = (u16*)(ws + (244L<<20));
  u16* gk_hi  = (u16*)(ws + (212L<<20));
  u16* gk_lo  = (u16*)(ws + (213L<<20));
  u16* gv_hi  = (u16*)(ws + (214L<<20));
  u16* gv_lo  = (u16*)(ws + (215L<<20));
  u16* attn_hi = (u16*)(ws + (244L<<20));

  const dim3 blk(256);
  const float scale = 0.125f;   // 1/sqrt(64)

  // 0) mask + weights + query conversion
  mask_norm<<<1, blk, 0, stream>>>(mask_raw, mask_ws, 16384);
  transpose_hi5<<<dim3(16,16,5), blk, 0, stream>>>(Wq, Wk, Wv, Wi, Wo,
      WqT_hi, WkT_hi, WvT_hi, WiT_hi, WoT_hi);
  conv_hi<<<8192, blk, 0, stream>>>(query, qp_hi, 2097152);

  // 1) PAIR1: {qs-proj | ips} merged, TM=256
  {
    PArg g0 = { qp_hi,  WqT_hi, qs_hi,  qs_lo,  0L, 0L,
                1024, 1024, 1024, 8, 64 };          // 8*64 = 512 blocks
    PArg g1 = { WiT_hi, qp_hi,  ips_hi, ips_lo, 2097152L, 2097152L,
                1024, 1024, 2048, 16, 4 };          // 16*4*8 = 512 blocks
    gemm_pair<256,1><<<1024, blk, 0, stream>>>(g0, g1, 512, 1024);
  }

  // 2) gqs = softmax(ips) @ qs  (fused flash, KC=4)
  flash_agg<1><<<dim3(4,128), blk, 0, stream>>>(
      ips_hi, ips_lo, qs_hi, qs_lo, nullptr, nullptr,
      partg, nullptr, msm_q, mss_q,
      2048, 4, 2048, 1024, 2097152L, 131072L, 2097152L, 64L, 16, 128);
  flash_combine<1,4><<<128, blk, 0, stream>>>(
      partg, nullptr, msm_q, mss_q, gqs_hi, gqs_lo, nullptr, nullptr, 128);

  // 3) PAIR2: {kk-proj | vs-proj} merged, TM=256, A from fp32 key/value
  {
    PArg g0 = { key,   WkT_hi, kk_hi, kk_lo, 0L, 0L, 1024, 1024, 1024, 8, 64 };
    PArg g1 = { value, WvT_hi, vs_hi, vs_lo, 0L, 0L, 1024, 1024, 1024, 8, 64 };
    gemm_pair<256,0><<<1024, blk, 0, stream>>>(g0, g1, 512, 1024);
  }

  // 4) g_scores (2-term A) -> planes; mask+scale in epilogue
  gemm_g<64,2,1,1,0><<<dim3(16,1,128), blk, 0, stream>>>(
      gqs_hi, gqs_lo, kk_hi, gsc_hi, gsc_lo, mask_ws,
      64, 64,1024,2048, 65536L,4096L, 2097152L,64L, 2097152L,131072L, 16, 2048, scale);

  // 5) gk/gv = softmax(g_scores) @ {kk,vs}  (fused dual flash, KC=4)
  flash_agg<2><<<dim3(4,128), blk, 0, stream>>>(
      gsc_hi, gsc_lo, kk_hi, kk_lo, vs_hi, vs_lo,
      part1, part2, msm_g, mss_g,
      2048, 4, 2048, 1024, 2097152L, 131072L, 2097152L, 64L, 16, 128);
  flash_combine<2,4><<<128, blk, 0, stream>>>(
      part1, part2, msm_g, mss_g, gk_hi, gk_lo, gv_hi, gv_lo, 128);

  // 6) stage 2 (MFMA): l_attn (out1) + attn hi plane
  stage2_mfma<<<dim3(16,128), blk, 0, stream>>>(qs_hi, qs_lo, gk_hi, gk_lo,
      gv_hi, gv_lo, out1, attn_hi, scale);

  // 7) out0 = attn @ Wo (TM=256, 1-term, swizzled)
  gemm_g<256,1,0,0,1><<<dim3(8,64,1), blk, 0, stream>>>(
      attn_hi, nullptr, WoT_hi, out0, nullptr, nullptr,
      1024, 1024,1024,1024, 0,0, 0,0, 0,0, 1, 2048, 1.f);

  (void)in_sizes; (void)n_in; (void)out_size; (void)ws_size;
}

// Round 14
// 516.768 us; speedup vs baseline: 1.2516x; 1.2516x over previous
//
#include <hip/hip_runtime.h>

// EGA multi-headed attention, MI355X/gfx950.
// Round 14: REVERT to r12 (best: 517us). TM=256 (r13) collapsed occupancy
//           (1 block/CU) and regressed 25% — 2-phase loop needs inter-block
//           TLP to hide barrier drains; big tiles need the 8-phase schedule.
// Dims fixed: B=8, L=S=2048, E=1024, H=16, G=64, Ek=Ev=64, KD=VD=1024.

typedef float f32x4 __attribute__((ext_vector_type(4)));
typedef _Float16 f16x8 __attribute__((ext_vector_type(8)));
typedef unsigned short u16;

#define DEV static __device__ __forceinline__

DEV u16 f2h(float x){
  _Float16 h = (_Float16)x;
  return __builtin_bit_cast(u16, h);
}
DEV float h2f(u16 u){
  return (float)__builtin_bit_cast(_Float16, u);
}
DEV void split1h(float x, u16 &h, u16 &l){
  h = f2h(x);
  l = f2h(x - h2f(h));
}
DEV unsigned pk2h(float a, float b){
  return (unsigned)f2h(a) | ((unsigned)f2h(b) << 16);
}

// async global->LDS, 16B per lane; dst is wave-uniform base (HW adds lane*16)
DEV void gload16(const u16* src, u16* dst_lds){
  __builtin_amdgcn_global_load_lds(
      (__attribute__((address_space(1))) void*)src,
      (__attribute__((address_space(3))) void*)dst_lds, 16, 0, 0);
}

// ---------------- mask dtype sniff + normalize to uchar ----------------
__global__ __launch_bounds__(256)
void mask_norm(const unsigned char* __restrict__ src, unsigned char* __restrict__ dst, int n)
{
  const unsigned* w = (const unsigned*)src;
  const int tid = threadIdx.x;
  int local = 0;
  for (int i = tid; i < n/4; i += 256){
    unsigned v = w[i];
    if (v == 0x3F800000u) local |= 2;
    else if (v > 1u)      local |= 1;
  }
  __shared__ int red[256];
  red[tid] = local;
  __syncthreads();
  for (int s = 128; s; s >>= 1){
    if (tid < s) red[tid] |= red[tid+s];
    __syncthreads();
  }
  const int r = red[0];
  const int mode = (r & 2) ? 2 : ((r & 1) ? 1 : 0);   // 2=f32, 1=u8, 0=i32
  for (int i = tid; i < n; i += 256){
    unsigned char v;
    if (mode == 1) v = src[i] ? 1 : 0;
    else           v = w[i]   ? 1 : 0;
    dst[i] = v;
  }
}

// ---------------- fp32 -> f16 hi plane (8 elems/thread) ----------------
__global__ __launch_bounds__(256)
void conv_hi(const float* __restrict__ x, u16* __restrict__ hi, int n8)
{
  const int i = blockIdx.x*256 + threadIdx.x;
  if (i >= n8) return;
  f32x4 a = ((const f32x4*)x)[2*i], b = ((const f32x4*)x)[2*i+1];
  uint4 uh;
  uh.x = pk2h(a[0], a[1]); uh.y = pk2h(a[2], a[3]);
  uh.z = pk2h(b[0], b[1]); uh.w = pk2h(b[2], b[3]);
  ((uint4*)hi)[i] = uh;
}

// ---------------- 5x 1024x1024 transpose, fp32 -> f16 hi plane (z selects) ----------------
__global__ __launch_bounds__(256)
void transpose_hi5(const float* __restrict__ s0, const float* __restrict__ s1,
                   const float* __restrict__ s2, const float* __restrict__ s3,
                   const float* __restrict__ s4,
                   u16* __restrict__ d0, u16* __restrict__ d1, u16* __restrict__ d2,
                   u16* __restrict__ d3, u16* __restrict__ d4)
{
  const int z = blockIdx.z;
  const float* Wsrc = z == 0 ? s0 : z == 1 ? s1 : z == 2 ? s2 : z == 3 ? s3 : s4;
  u16* Whi = z == 0 ? d0 : z == 1 ? d1 : z == 2 ? d2 : z == 3 ? d3 : d4;
  __shared__ float t[64][65];
  const int tid = threadIdx.x;
  const int n0 = blockIdx.x * 64, k0 = blockIdx.y * 64;
  #pragma unroll
  for (int it = 0; it < 16; ++it){
    int e = it*256 + tid, r = e >> 6, c = e & 63;
    t[r][c] = Wsrc[(long)(k0+r)*1024 + (n0+c)];
  }
  __syncthreads();
  #pragma unroll
  for (int it = 0; it < 16; ++it){
    int e = it*256 + tid, r = e >> 6, c = e & 63;
    Whi[(long)(n0+r)*1024 + (k0+c)] = f2h(t[c][r]);
  }
}

// ---------------- f16 MFMA GEMM, global_load_lds staging, dbuf (r8 loop) ----------------
template<int TM, int TERMS, int CM, int EPI, int SWZ>
__global__ __launch_bounds__(256)
void gemm_g(const u16* __restrict__ Ah_g, const u16* __restrict__ Al_g,
            const u16* __restrict__ Bh_g,
            void* __restrict__ Cp, void* __restrict__ Cp2,
            const unsigned char* __restrict__ maskp,
            int K, int lda, int ldb, int ldc,
            long aB, long aH, long bB, long bH, long cB, long cH,
            int H2, int Ssz, float scale)
{
  constexpr int BN = 128, BK = 32;
  constexpr int WM = TM/2, WN = BN/2;
  constexpr int FM = WM/16, FN = WN/16;
  __shared__ __align__(16) u16 AhS[2][TM*BK];
  __shared__ __align__(16) u16 AlS[2][TERMS == 2 ? TM*BK : 8];
  __shared__ __align__(16) u16 BhS[2][BN*BK];

  const int tid = threadIdx.x;
  int bx = blockIdx.x, by = blockIdx.y;
  if constexpr (SWZ){
    const int gx = gridDim.x;
    const int nwg = gx * gridDim.y;
    const int q = nwg >> 3;
    const int flat = bx + gx * by;
    const int nf = (flat & 7) * q + (flat >> 3);
    bx = nf % gx; by = nf / gx;
  }
  const int batch = blockIdx.z;
  const int b = batch / H2, h = batch - b*H2;
  const long aOff = (long)b*aB + (long)h*aH;
  const long bOff = (long)b*bB + (long)h*bH;
  const long cOff = (long)b*cB + (long)h*cH;
  const int nBase = bx * BN;
  const int mBase = by * TM;
  const int wave = tid >> 6, lane = tid & 63;
  const int wm = wave >> 1, wn = wave & 1;
  const int cg8 = (lane & 3) * 8;
  const int rsub = lane >> 2;

  auto stage = [&](int buf, int k0){
    #pragma unroll
    for (int c = 0; c < TM/64; ++c){
      const int chunk = wave*(TM/64) + c;
      const long g = aOff + (long)(mBase + chunk*16 + rsub)*lda + k0 + cg8;
      gload16(Ah_g + g, &AhS[buf][chunk*512]);
      if constexpr (TERMS == 2) gload16(Al_g + g, &AlS[buf][chunk*512]);
    }
    #pragma unroll
    for (int c = 0; c < 2; ++c){
      const int chunk = wave*2 + c;
      const long g = bOff + (long)(nBase + chunk*16 + rsub)*ldb + k0 + cg8;
      gload16(Bh_g + g, &BhS[buf][chunk*512]);
    }
  };

  f32x4 acc[FM][FN] = {};

  stage(0, 0);
  __syncthreads();
  const int nk = K >> 5;
  for (int t = 0; t < nk; ++t){
    const int buf = t & 1;
    if (t + 1 < nk) stage(buf ^ 1, (t + 1) << 5);

    f16x8 ah[FM], al[FM], bh[FN];
    #pragma unroll
    for (int mi = 0; mi < FM; ++mi){
      const int off = (wm*WM + mi*16 + (lane & 15))*BK + (lane >> 4)*8;
      ah[mi] = *(const f16x8*)&AhS[buf][off];
      if constexpr (TERMS == 2) al[mi] = *(const f16x8*)&AlS[buf][off];
    }
    #pragma unroll
    for (int ni = 0; ni < FN; ++ni){
      const int off = (wn*WN + ni*16 + (lane & 15))*BK + (lane >> 4)*8;
      bh[ni] = *(const f16x8*)&BhS[buf][off];
    }
    #pragma unroll
    for (int mi = 0; mi < FM; ++mi)
      #pragma unroll
      for (int ni = 0; ni < FN; ++ni){
        acc[mi][ni] = __builtin_amdgcn_mfma_f32_16x16x32_f16(ah[mi], bh[ni], acc[mi][ni], 0, 0, 0);
        if constexpr (TERMS == 2)
          acc[mi][ni] = __builtin_amdgcn_mfma_f32_16x16x32_f16(al[mi], bh[ni], acc[mi][ni], 0, 0, 0);
      }
    __syncthreads();
  }

  const int cr = (lane >> 4) * 4, cc = lane & 15;
  #pragma unroll
  for (int mi = 0; mi < FM; ++mi)
    #pragma unroll
    for (int ni = 0; ni < FN; ++ni)
      #pragma unroll
      for (int r = 0; r < 4; ++r){
        const int row = mBase + wm*WM + mi*16 + cr + r;
        const int col = nBase + wn*WN + ni*16 + cc;
        float v = acc[mi][ni][r];
        if constexpr (EPI == 1){
          v *= scale;
          if (maskp[(long)b*Ssz + col]) v = -50000.0f;
        }
        const long ci = cOff + (long)row*ldc + col;
        if constexpr (CM == 0){
          ((float*)Cp)[ci] = v;
        } else {
          u16 hh, ll;
          split1h(v, hh, ll);
          ((u16*)Cp)[ci]  = hh;
          ((u16*)Cp2)[ci] = ll;
        }
      }
}

// ---------------- merged dual-GEMM dispatch (1-term A, planes out) ----------------
struct PArg {
  const void* Ap;        // u16 plane (AMODE=1) or f32 (AMODE=0)
  const u16*  Bh;
  u16* Ch; u16* Cl;
  long bB, cB;           // z strides for B and C (A has none)
  int lda, ldb, ldc;
  int nbx, nby;
};

template<int TM, int AMODE>
__global__ __launch_bounds__(256)
void gemm_pair(PArg a0, PArg a1, int n0, int K)
{
  constexpr int BN = 128, BK = 32;
  constexpr int WM = TM/2, WN = BN/2;
  constexpr int FM = WM/16, FN = WN/16;
  constexpr int NC = TM/64;                 // A chunks per thread
  __shared__ __align__(16) u16 AhS[2][TM*BK];
  __shared__ __align__(16) u16 BhS[2][BN*BK];

  const int tid = threadIdx.x;
  const int gid = blockIdx.x;
  const PArg P = (gid < n0) ? a0 : a1;
  int lid = (gid < n0) ? gid : gid - n0;
  const int gsz = (gid < n0) ? n0 : ((int)gridDim.x - n0);
  {
    const int q = gsz >> 3;
    lid = (lid & 7) * q + (lid >> 3);
  }
  const int bx = lid % P.nbx;
  const int rest = lid / P.nbx;
  const int by = rest % P.nby;
  const int z  = rest / P.nby;
  const long bOff = (long)z * P.bB;
  const long cOff = (long)z * P.cB;
  const int nBase = bx * BN;
  const int mBase = by * TM;
  const int wave = tid >> 6, lane = tid & 63;
  const int wm = wave >> 1, wn = wave & 1;
  const int cg8 = (lane & 3) * 8;
  const int rsub = lane >> 2;

  const u16* Au = (const u16*)P.Ap;
  const float* Af = (const float*)P.Ap;

  auto stageB = [&](int buf, int k0){
    #pragma unroll
    for (int c = 0; c < 2; ++c){
      const int chunk = wave*2 + c;
      const long g = bOff + (long)(nBase + chunk*16 + rsub)*P.ldb + k0 + cg8;
      gload16(P.Bh + g, &BhS[buf][chunk*512]);
    }
  };
  auto stageA_g = [&](int buf, int k0){
    #pragma unroll
    for (int c = 0; c < NC; ++c){
      const int chunk = wave*NC + c;
      const long g = (long)(mBase + chunk*16 + rsub)*P.lda + k0 + cg8;
      gload16(Au + g, &AhS[buf][chunk*512]);
    }
  };

  f32x4 acc[FM][FN] = {};
  f32x4 sA0[NC], sA1[NC];

  auto loadA_f = [&](int k0){
    #pragma unroll
    for (int c = 0; c < NC; ++c){
      const int chunk = wave*NC + c;
      const long g = (long)(mBase + chunk*16 + rsub)*P.lda + k0 + cg8;
      sA0[c] = *(const f32x4*)(Af + g);
      sA1[c] = *(const f32x4*)(Af + g + 4);
    }
  };
  auto writeA_f = [&](int buf){
    #pragma unroll
    for (int c = 0; c < NC; ++c){
      const int chunk = wave*NC + c;
      uint4 u;
      u.x = pk2h(sA0[c][0], sA0[c][1]); u.y = pk2h(sA0[c][2], sA0[c][3]);
      u.z = pk2h(sA1[c][0], sA1[c][1]); u.w = pk2h(sA1[c][2], sA1[c][3]);
      *(uint4*)&AhS[buf][chunk*512 + (long)lane*8] = u;
    }
  };

  stageB(0, 0);
  if constexpr (AMODE == 1) stageA_g(0, 0);
  else { loadA_f(0); writeA_f(0); }
  __syncthreads();

  const int nk = K >> 5;
  for (int t = 0; t < nk; ++t){
    const int buf = t & 1;
    if (t + 1 < nk){
      stageB(buf ^ 1, (t + 1) << 5);
      if constexpr (AMODE == 1) stageA_g(buf ^ 1, (t + 1) << 5);
      else loadA_f((t + 1) << 5);
    }

    f16x8 ah[FM], bh[FN];
    #pragma unroll
    for (int mi = 0; mi < FM; ++mi){
      const int off = (wm*WM + mi*16 + (lane & 15))*BK + (lane >> 4)*8;
      ah[mi] = *(const f16x8*)&AhS[buf][off];
    }
    #pragma unroll
    for (int ni = 0; ni < FN; ++ni){
      const int off = (wn*WN + ni*16 + (lane & 15))*BK + (lane >> 4)*8;
      bh[ni] = *(const f16x8*)&BhS[buf][off];
    }
    #pragma unroll
    for (int mi = 0; mi < FM; ++mi)
      #pragma unroll
      for (int ni = 0; ni < FN; ++ni)
        acc[mi][ni] = __builtin_amdgcn_mfma_f32_16x16x32_f16(ah[mi], bh[ni], acc[mi][ni], 0, 0, 0);

    if constexpr (AMODE == 0){
      if (t + 1 < nk) writeA_f(buf ^ 1);
    }
    __syncthreads();
  }

  const int cr = (lane >> 4) * 4, cc = lane & 15;
  #pragma unroll
  for (int mi = 0; mi < FM; ++mi)
    #pragma unroll
    for (int ni = 0; ni < FN; ++ni)
      #pragma unroll
      for (int r = 0; r < 4; ++r){
        const int row = mBase + wm*WM + mi*16 + cr + r;
        const int col = nBase + wn*WN + ni*16 + cc;
        const long ci = cOff + (long)row*P.ldc + col;
        u16 hh, ll;
        split1h(acc[mi][ni][r], hh, ll);
        P.Ch[ci] = hh;
        P.Cl[ci] = ll;
      }
}

// ---------------- flash aggregation v2 ----------------
template<int NB>
__global__ __launch_bounds__(256)
void flash_agg(const u16* __restrict__ Sh_g, const u16* __restrict__ Sl_g,
               const u16* __restrict__ B1h_g, const u16* __restrict__ B1l_g,
               const u16* __restrict__ B2h_g, const u16* __restrict__ B2l_g,
               float* __restrict__ P1, float* __restrict__ P2,
               float* __restrict__ msm, float* __restrict__ mss,
               int K, int KC, int lda, int ldb,
               long aB, long aH, long bB, long bH, int H2, int nbatch)
{
  __shared__ __align__(16) u16 Ph[64][72], Pl[64][72];
  __shared__ __align__(16) u16 B1hS[64][72], B1lS[64][72];
  __shared__ __align__(16) u16 B2hS[NB==2?64:1][72], B2lS[NB==2?64:1][72];
  __shared__ float mS[64], sS[64], fS[64];
  const int tid = threadIdx.x;
  const int kc = blockIdx.x, batch = blockIdx.y;
  const int b = batch / H2, h = batch - b*H2;
  const long aOff = (long)b*aB + (long)h*aH;
  const long bOff = (long)b*bB + (long)h*bH;
  const int kchunk = K / KC, kbeg = kc * kchunk;
  const int wm = tid >> 6, lane = tid & 63;
  const int srow = tid >> 2, sq = tid & 3;

  if (tid < 64){ mS[tid] = -1e30f; sS[tid] = 0.f; }

  f32x4 acc1[4] = {}, acc2[4] = {};

  for (int ks = kbeg; ks < kbeg + kchunk; ks += 64){
    __syncthreads();
    #pragma unroll
    for (int it = 0; it < 4; ++it){
      const int e = it*256 + tid;
      const int lr = e >> 4, d0 = (e & 15) * 4;
      const long gm = bOff + (long)(ks + lr)*ldb + d0;
      ushort4 h4 = *(const ushort4*)(B1h_g + gm);
      ushort4 l4 = *(const ushort4*)(B1l_g + gm);
      B1hS[d0+0][lr]=h4.x; B1hS[d0+1][lr]=h4.y; B1hS[d0+2][lr]=h4.z; B1hS[d0+3][lr]=h4.w;
      B1lS[d0+0][lr]=l4.x; B1lS[d0+1][lr]=l4.y; B1lS[d0+2][lr]=l4.z; B1lS[d0+3][lr]=l4.w;
      if constexpr (NB == 2){
        ushort4 h42 = *(const ushort4*)(B2h_g + gm);
        ushort4 l42 = *(const ushort4*)(B2l_g + gm);
        B2hS[d0+0][lr]=h42.x; B2hS[d0+1][lr]=h42.y; B2hS[d0+2][lr]=h42.z; B2hS[d0+3][lr]=h42.w;
        B2lS[d0+0][lr]=l42.x; B2lS[d0+1][lr]=l42.y; B2lS[d0+2][lr]=l42.z; B2lS[d0+3][lr]=l42.w;
      }
    }

    float v[16];
    {
      const long ga = aOff + (long)srow*lda + ks + sq*16;
      uint4 ha = *(const uint4*)(Sh_g + ga);
      uint4 hb = *(const uint4*)(Sh_g + ga + 8);
      uint4 la = *(const uint4*)(Sl_g + ga);
      uint4 lb = *(const uint4*)(Sl_g + ga + 8);
      v[0]=h2f((u16)ha.x)+h2f((u16)la.x);  v[1]=h2f((u16)(ha.x>>16))+h2f((u16)(la.x>>16));
      v[2]=h2f((u16)ha.y)+h2f((u16)la.y);  v[3]=h2f((u16)(ha.y>>16))+h2f((u16)(la.y>>16));
      v[4]=h2f((u16)ha.z)+h2f((u16)la.z);  v[5]=h2f((u16)(ha.z>>16))+h2f((u16)(la.z>>16));
      v[6]=h2f((u16)ha.w)+h2f((u16)la.w);  v[7]=h2f((u16)(ha.w>>16))+h2f((u16)(la.w>>16));
      v[8]=h2f((u16)hb.x)+h2f((u16)lb.x);  v[9]=h2f((u16)(hb.x>>16))+h2f((u16)(lb.x>>16));
      v[10]=h2f((u16)hb.y)+h2f((u16)lb.y); v[11]=h2f((u16)(hb.y>>16))+h2f((u16)(lb.y>>16));
      v[12]=h2f((u16)hb.z)+h2f((u16)lb.z); v[13]=h2f((u16)(hb.z>>16))+h2f((u16)(lb.z>>16));
      v[14]=h2f((u16)hb.w)+h2f((u16)lb.w); v[15]=h2f((u16)(hb.w>>16))+h2f((u16)(lb.w>>16));
    }
    float mx = v[0];
    #pragma unroll
    for (int i = 1; i < 16; ++i) mx = fmaxf(mx, v[i]);
    mx = fmaxf(mx, __shfl_xor(mx, 1));
    mx = fmaxf(mx, __shfl_xor(mx, 2));
    const float mold = mS[srow];
    const float mnew = fmaxf(mold, mx);
    float sum = 0.f;
    u16 ph[16], pl[16];
    #pragma unroll
    for (int i = 0; i < 16; ++i){
      float e = __expf(v[i] - mnew);
      sum += e;
      split1h(e, ph[i], pl[i]);
    }
    sum += __shfl_xor(sum, 1);
    sum += __shfl_xor(sum, 2);
    if (sq == 0){
      const float f = __expf(mold - mnew);
      sS[srow] = sS[srow] * f + sum;
      mS[srow] = mnew;
      fS[srow] = f;
    }
    {
      uint4 uh0, uh1, ul0, ul1;
      uh0.x=(unsigned)ph[0]|((unsigned)ph[1]<<16);  uh0.y=(unsigned)ph[2]|((unsigned)ph[3]<<16);
      uh0.z=(unsigned)ph[4]|((unsigned)ph[5]<<16);  uh0.w=(unsigned)ph[6]|((unsigned)ph[7]<<16);
      uh1.x=(unsigned)ph[8]|((unsigned)ph[9]<<16);  uh1.y=(unsigned)ph[10]|((unsigned)ph[11]<<16);
      uh1.z=(unsigned)ph[12]|((unsigned)ph[13]<<16);uh1.w=(unsigned)ph[14]|((unsigned)ph[15]<<16);
      ul0.x=(unsigned)pl[0]|((unsigned)pl[1]<<16);  ul0.y=(unsigned)pl[2]|((unsigned)pl[3]<<16);
      ul0.z=(unsigned)pl[4]|((unsigned)pl[5]<<16);  ul0.w=(unsigned)pl[6]|((unsigned)pl[7]<<16);
      ul1.x=(unsigned)pl[8]|((unsigned)pl[9]<<16);  ul1.y=(unsigned)pl[10]|((unsigned)pl[11]<<16);
      ul1.z=(unsigned)pl[12]|((unsigned)pl[13]<<16);ul1.w=(unsigned)pl[14]|((unsigned)pl[15]<<16);
      *(uint4*)&Ph[srow][sq*16]     = uh0;
      *(uint4*)&Ph[srow][sq*16 + 8] = uh1;
      *(uint4*)&Pl[srow][sq*16]     = ul0;
      *(uint4*)&Pl[srow][sq*16 + 8] = ul1;
    }
    __syncthreads();

    float fr4[4];
    #pragma unroll
    for (int r = 0; r < 4; ++r) fr4[r] = fS[wm*16 + (lane >> 4)*4 + r];
    #pragma unroll
    for (int ni = 0; ni < 4; ++ni)
      #pragma unroll
      for (int r = 0; r < 4; ++r){
        acc1[ni][r] *= fr4[r];
        if constexpr (NB == 2) acc2[ni][r] *= fr4[r];
      }
    #pragma unroll
    for (int k0 = 0; k0 < 64; k0 += 32){
      const int ko = k0 + (lane >> 4)*8;
      const int fr = lane & 15;
      f16x8 a_h = *(const f16x8*)&Ph[wm*16 + fr][ko];
      f16x8 a_l = *(const f16x8*)&Pl[wm*16 + fr][ko];
      #pragma unroll
      for (int ni = 0; ni < 4; ++ni){
        f16x8 b_h = *(const f16x8*)&B1hS[ni*16 + fr][ko];
        f16x8 b_l = *(const f16x8*)&B1lS[ni*16 + fr][ko];
        acc1[ni] = __builtin_amdgcn_mfma_f32_16x16x32_f16(a_h, b_h, acc1[ni], 0, 0, 0);
        acc1[ni] = __builtin_amdgcn_mfma_f32_16x16x32_f16(a_l, b_h, acc1[ni], 0, 0, 0);
        acc1[ni] = __builtin_amdgcn_mfma_f32_16x16x32_f16(a_h, b_l, acc1[ni], 0, 0, 0);
        if constexpr (NB == 2){
          f16x8 c_h = *(const f16x8*)&B2hS[ni*16 + fr][ko];
          f16x8 c_l = *(const f16x8*)&B2lS[ni*16 + fr][ko];
          acc2[ni] = __builtin_amdgcn_mfma_f32_16x16x32_f16(a_h, c_h, acc2[ni], 0, 0, 0);
          acc2[ni] = __builtin_amdgcn_mfma_f32_16x16x32_f16(a_l, c_h, acc2[ni], 0, 0, 0);
          acc2[ni] = __builtin_amdgcn_mfma_f32_16x16x32_f16(a_h, c_l, acc2[ni], 0, 0, 0);
        }
      }
    }
  }

  const long po = ((long)(kc*nbatch + batch) << 12);
  const int cr = (lane >> 4) * 4, cc = lane & 15;
  #pragma unroll
  for (int ni = 0; ni < 4; ++ni)
    #pragma unroll
    for (int r = 0; r < 4; ++r){
      const int g = wm*16 + cr + r, d = ni*16 + cc;
      P1[po + g*64 + d] = acc1[ni][r];
      if constexpr (NB == 2) P2[po + g*64 + d] = acc2[ni][r];
    }
  if (tid < 64){
    msm[((long)kc*nbatch + batch)*64 + tid] = mS[tid];
    mss[((long)kc*nbatch + batch)*64 + tid] = sS[tid];
  }
}

// ---------------- exact cross-chunk combine (compile-time KC) ----------------
template<int NB, int KC>
__global__ __launch_bounds__(256)
void flash_combine(const float* __restrict__ P1, const float* __restrict__ P2,
                   const float* __restrict__ msm, const float* __restrict__ mss,
                   u16* __restrict__ o1h, u16* __restrict__ o1l,
                   u16* __restrict__ o2h, u16* __restrict__ o2l, int nbatch)
{
  const int batch = blockIdx.x;
  const int tid = threadIdx.x;
  const int g = tid >> 2, dq = (tid & 3) * 16;
  float m[KC], s[KC], w[KC];
  float M = -1e30f;
  #pragma unroll
  for (int c = 0; c < KC; ++c){
    m[c] = msm[((long)c*nbatch + batch)*64 + g];
    s[c] = mss[((long)c*nbatch + batch)*64 + g];
    M = fmaxf(M, m[c]);
  }
  float den = 0.f;
  #pragma unroll
  for (int c = 0; c < KC; ++c){ w[c] = __expf(m[c] - M); den += s[c]*w[c]; }
  const float inv = 1.0f / den;
  #pragma unroll
  for (int c = 0; c < KC; ++c) w[c] *= inv;
  const long oo = (long)batch*4096 + g*64 + dq;
  #pragma unroll
  for (int nb = 0; nb < NB; ++nb){
    const float* Pa = nb ? P2 : P1;
    u16* oh = nb ? o2h : o1h;
    u16* ol = nb ? o2l : o1l;
    u16 hh[16], ll[16];
    #pragma unroll
    for (int j = 0; j < 4; ++j){
      f32x4 a = {0.f, 0.f, 0.f, 0.f};
      #pragma unroll
      for (int c = 0; c < KC; ++c){
        f32x4 p = *(const f32x4*)(Pa + (((long)c*nbatch + batch) << 12) + g*64 + dq + j*4);
        a += p * w[c];
      }
      #pragma unroll
      for (int e = 0; e < 4; ++e) split1h(a[e], hh[j*4+e], ll[j*4+e]);
    }
    uint4 uh0, uh1, ul0, ul1;
    uh0.x=(unsigned)hh[0]|((unsigned)hh[1]<<16);  uh0.y=(unsigned)hh[2]|((unsigned)hh[3]<<16);
    uh0.z=(unsigned)hh[4]|((unsigned)hh[5]<<16);  uh0.w=(unsigned)hh[6]|((unsigned)hh[7]<<16);
    uh1.x=(unsigned)hh[8]|((unsigned)hh[9]<<16);  uh1.y=(unsigned)hh[10]|((unsigned)hh[11]<<16);
    uh1.z=(unsigned)hh[12]|((unsigned)hh[13]<<16);uh1.w=(unsigned)hh[14]|((unsigned)hh[15]<<16);
    ul0.x=(unsigned)ll[0]|((unsigned)ll[1]<<16);  ul0.y=(unsigned)ll[2]|((unsigned)ll[3]<<16);
    ul0.z=(unsigned)ll[4]|((unsigned)ll[5]<<16);  ul0.w=(unsigned)ll[6]|((unsigned)ll[7]<<16);
    ul1.x=(unsigned)ll[8]|((unsigned)ll[9]<<16);  ul1.y=(unsigned)ll[10]|((unsigned)ll[11]<<16);
    ul1.z=(unsigned)ll[12]|((unsigned)ll[13]<<16);ul1.w=(unsigned)ll[14]|((unsigned)ll[15]<<16);
    *(uint4*)(oh + oo)     = uh0;
    *(uint4*)(oh + oo + 8) = uh1;
    *(uint4*)(ol + oo)     = ul0;
    *(uint4*)(ol + oo + 8) = ul1;
  }
}

// ---------------- stage 2, MFMA ----------------
__global__ __launch_bounds__(256)
void stage2_mfma(const u16* __restrict__ qhi, const u16* __restrict__ qlo,
                 const u16* __restrict__ gkh_g, const u16* __restrict__ gkl_g,
                 const u16* __restrict__ gvh_g, const u16* __restrict__ gvl_g,
                 float* __restrict__ lattn, u16* __restrict__ ahi,
                 float scale)
{
  __shared__ __align__(16) u16 Ah[128][72];
  __shared__ __align__(16) u16 Al[128][72];
  __shared__ __align__(16) u16 Bh[64][72];
  __shared__ __align__(16) u16 Bl[64][72];
  const int tid = threadIdx.x;
  const int bh = blockIdx.y;
  const int b = bh >> 4, h = bh & 15;
  const int l0 = blockIdx.x * 128;
  const int wm = tid >> 6, lane = tid & 63;

  const long qbase = ((long)b*2048 + l0)*1024 + h*64;
  #pragma unroll
  for (int it = 0; it < 4; ++it){
    const int e = it*256 + tid, row = e >> 3, s = e & 7;
    const long g = qbase + (long)row*1024 + s*8;
    *(uint4*)&Ah[row][s*8] = *(const uint4*)(qhi + g);
    *(uint4*)&Al[row][s*8] = *(const uint4*)(qlo + g);
  }
  const long gb = (long)bh * 4096;
  #pragma unroll
  for (int it = 0; it < 2; ++it){
    const int e = it*256 + tid, gr = e >> 3, s = e & 7;
    *(uint4*)&Bh[gr][s*8] = *(const uint4*)(gkh_g + gb + gr*64 + s*8);
    *(uint4*)&Bl[gr][s*8] = *(const uint4*)(gkl_g + gb + gr*64 + s*8);
  }
  __syncthreads();

  f32x4 acc[2][4] = {};
  #pragma unroll
  for (int k0 = 0; k0 < 64; k0 += 32){
    f16x8 a_h[2], a_l[2], b_h[4], b_l[4];
    #pragma unroll
    for (int mi = 0; mi < 2; ++mi){
      const int row = wm*32 + mi*16 + (lane & 15);
      a_h[mi] = *(const f16x8*)&Ah[row][k0 + (lane >> 4)*8];
      a_l[mi] = *(const f16x8*)&Al[row][k0 + (lane >> 4)*8];
    }
    #pragma unroll
    for (int ni = 0; ni < 4; ++ni){
      const int nr = ni*16 + (lane & 15);
      b_h[ni] = *(const f16x8*)&Bh[nr][k0 + (lane >> 4)*8];
      b_l[ni] = *(const f16x8*)&Bl[nr][k0 + (lane >> 4)*8];
    }
    #pragma unroll
    for (int mi = 0; mi < 2; ++mi)
      #pragma unroll
      for (int ni = 0; ni < 4; ++ni){
        acc[mi][ni] = __builtin_amdgcn_mfma_f32_16x16x32_f16(a_h[mi], b_h[ni], acc[mi][ni], 0, 0, 0);
        acc[mi][ni] = __builtin_amdgcn_mfma_f32_16x16x32_f16(a_l[mi], b_h[ni], acc[mi][ni], 0, 0, 0);
        acc[mi][ni] = __builtin_amdgcn_mfma_f32_16x16x32_f16(a_h[mi], b_l[ni], acc[mi][ni], 0, 0, 0);
      }
  }
  __syncthreads();

  #pragma unroll
  for (int it = 0; it < 4; ++it){
    const int e = it*256 + tid;
    const int gr = e >> 4, d0 = (e & 15) * 4;
    ushort4 vh = *(const ushort4*)(gvh_g + gb + gr*64 + d0);
    ushort4 vl = *(const ushort4*)(gvl_g + gb + gr*64 + d0);
    Bh[d0+0][gr] = vh.x; Bh[d0+1][gr] = vh.y; Bh[d0+2][gr] = vh.z; Bh[d0+3][gr] = vh.w;
    Bl[d0+0][gr] = vl.x; Bl[d0+1][gr] = vl.y; Bl[d0+2][gr] = vl.z; Bl[d0+3][gr] = vl.w;
  }

  #pragma unroll
  for (int mi = 0; mi < 2; ++mi){
    #pragma unroll
    for (int r = 0; r < 4; ++r){
      float v0 = acc[mi][0][r]*scale, v1 = acc[mi][1][r]*scale;
      float v2 = acc[mi][2][r]*scale, v3 = acc[mi][3][r]*scale;
      float mx = fmaxf(fmaxf(v0,v1), fmaxf(v2,v3));
      #pragma unroll
      for (int off = 1; off < 16; off <<= 1) mx = fmaxf(mx, __shfl_xor(mx, off, 16));
      float e0 = __expf(v0-mx), e1 = __expf(v1-mx), e2 = __expf(v2-mx), e3 = __expf(v3-mx);
      float sum = (e0+e1) + (e2+e3);
      #pragma unroll
      for (int off = 1; off < 16; off <<= 1) sum += __shfl_xor(sum, off, 16);
      const float inv = 1.0f / sum;
      e0 *= inv; e1 *= inv; e2 *= inv; e3 *= inv;
      const int lrow = wm*32 + mi*16 + (lane >> 4)*4 + r;
      float* lp = lattn + ((long)bh*2048 + l0 + lrow)*64 + (lane & 15);
      lp[0] = e0; lp[16] = e1; lp[32] = e2; lp[48] = e3;
      u16 hh, ll;
      split1h(e0, hh, ll); Ah[lrow][ 0 + (lane&15)] = hh; Al[lrow][ 0 + (lane&15)] = ll;
      split1h(e1, hh, ll); Ah[lrow][16 + (lane&15)] = hh; Al[lrow][16 + (lane&15)] = ll;
      split1h(e2, hh, ll); Ah[lrow][32 + (lane&15)] = hh; Al[lrow][32 + (lane&15)] = ll;
      split1h(e3, hh, ll); Ah[lrow][48 + (lane&15)] = hh; Al[lrow][48 + (lane&15)] = ll;
    }
  }
  __syncthreads();

  f32x4 o[2][4] = {};
  #pragma unroll
  for (int k0 = 0; k0 < 64; k0 += 32){
    f16x8 p_h[2], p_l[2], b_h[4], b_l[4];
    #pragma unroll
    for (int mi = 0; mi < 2; ++mi){
      const int row = wm*32 + mi*16 + (lane & 15);
      p_h[mi] = *(const f16x8*)&Ah[row][k0 + (lane >> 4)*8];
      p_l[mi] = *(const f16x8*)&Al[row][k0 + (lane >> 4)*8];
    }
    #pragma unroll
    for (int ni = 0; ni < 4; ++ni){
      const int nr = ni*16 + (lane & 15);
      b_h[ni] = *(const f16x8*)&Bh[nr][k0 + (lane >> 4)*8];
      b_l[ni] = *(const f16x8*)&Bl[nr][k0 + (lane >> 4)*8];
    }
    #pragma unroll
    for (int mi = 0; mi < 2; ++mi)
      #pragma unroll
      for (int ni = 0; ni < 4; ++ni){
        o[mi][ni] = __builtin_amdgcn_mfma_f32_16x16x32_f16(p_h[mi], b_h[ni], o[mi][ni], 0, 0, 0);
        o[mi][ni] = __builtin_amdgcn_mfma_f32_16x16x32_f16(p_l[mi], b_h[ni], o[mi][ni], 0, 0, 0);
        o[mi][ni] = __builtin_amdgcn_mfma_f32_16x16x32_f16(p_h[mi], b_l[ni], o[mi][ni], 0, 0, 0);
      }
  }

  #pragma unroll
  for (int mi = 0; mi < 2; ++mi)
    #pragma unroll
    for (int ni = 0; ni < 4; ++ni)
      #pragma unroll
      for (int r = 0; r < 4; ++r){
        const int lrow = wm*32 + mi*16 + (lane >> 4)*4 + r;
        const int d = ni*16 + (lane & 15);
        const long oidx = ((long)b*2048 + l0 + lrow)*1024 + h*64 + d;
        ahi[oidx] = f2h(o[mi][ni][r]);
      }
}

extern "C" void kernel_launch(void* const* d_in, const int* in_sizes, int n_in,
                              void* d_out, int out_size, void* d_ws, size_t ws_size,
                              hipStream_t stream)
{
  const float* query = (const float*)d_in[0];
  const float* key   = (const float*)d_in[1];
  const float* value = (const float*)d_in[2];
  const unsigned char* mask_raw = (const unsigned char*)d_in[4];
  const float* Wq = (const float*)d_in[6];
  const float* Wk = (const float*)d_in[7];
  const float* Wv = (const float*)d_in[8];
  const float* Wi = (const float*)d_in[9];
  const float* Wo = (const float*)d_in[10];
  float* out0 = (float*)d_out;                  // (B,L,E)
  float* out1 = out0 + 16777216;                // (B,H,L,G)

  // ---- workspace map (MiB), liveness-checked (same as r12) ----
  char* ws = (char*)d_ws;
  u16* WoT_hi = (u16*)(ws + 0);
  float* msm_q = (float*)(ws + (2L<<20));
  float* mss_q = (float*)(ws + (2L<<20) + 262144);
  float* msm_g = (float*)(ws + (3L<<20));
  float* mss_g = (float*)(ws + (3L<<20) + 262144);
  u16* WqT_hi = (u16*)(ws + (4L<<20));
  unsigned char* mask_ws = (unsigned char*)(ws + (6L<<20));
  float* part1 = (float*)(ws + (4L<<20));
  u16* WkT_hi = (u16*)(ws + (8L<<20));
  u16* WvT_hi = (u16*)(ws + (12L<<20));
  float* part2 = (float*)(ws + (12L<<20));
  u16* gqs_hi = (u16*)(ws + (16L<<20));
  u16* gqs_lo = (u16*)(ws + (17L<<20));
  u16* WiT_hi = (u16*)(ws + (18L<<20));
  u16* qp_hi  = (u16*)(ws + (20L<<20));
  u16* gsc_hi = (u16*)(ws + (20L<<20));
  u16* gsc_lo = (u16*)(ws + (52L<<20));
  u16* qs_hi  = (u16*)(ws + (84L<<20));
  u16* qs_lo  = (u16*)(ws + (116L<<20));
  float* partg = (float*)(ws + (148L<<20));
  u16* vs_hi  = (u16*)(ws + (148L<<20));
  u16* vs_lo  = (u16*)(ws + (180L<<20));
  u16* ips_hi = (u16*)(ws + (212L<<20));
  u16* ips_lo = (u16*)(ws + (244L<<20));
  u16* kk_hi  = (u16*)(ws + (212L<<20));
  u16* kk_lo  = (u16*)(ws + (244L<<20));
  u16* gk_hi  = (u16*)(ws + (212L<<20));
  u16* gk_lo  = (u16*)(ws + (213L<<20));
  u16* gv_hi  = (u16*)(ws + (214L<<20));
  u16* gv_lo  = (u16*)(ws + (215L<<20));
  u16* attn_hi = (u16*)(ws + (244L<<20));

  const dim3 blk(256);
  const float scale = 0.125f;   // 1/sqrt(64)

  // 0) mask + weights + query conversion
  mask_norm<<<1, blk, 0, stream>>>(mask_raw, mask_ws, 16384);
  transpose_hi5<<<dim3(16,16,5), blk, 0, stream>>>(Wq, Wk, Wv, Wi, Wo,
      WqT_hi, WkT_hi, WvT_hi, WiT_hi, WoT_hi);
  conv_hi<<<8192, blk, 0, stream>>>(query, qp_hi, 2097152);

  // 1) PAIR1: {qs-proj | ips} merged (both read qp; planes out), TM=128
  {
    PArg g0 = { qp_hi,  WqT_hi, qs_hi,  qs_lo,  0L, 0L,
                1024, 1024, 1024, 8, 128 };
    PArg g1 = { WiT_hi, qp_hi,  ips_hi, ips_lo, 2097152L, 2097152L,
                1024, 1024, 2048, 16, 8 };
    gemm_pair<128,1><<<2048, blk, 0, stream>>>(g0, g1, 1024, 1024);
  }

  // 2) gqs = softmax(ips) @ qs  (fused flash, KC=4)
  flash_agg<1><<<dim3(4,128), blk, 0, stream>>>(
      ips_hi, ips_lo, qs_hi, qs_lo, nullptr, nullptr,
      partg, nullptr, msm_q, mss_q,
      2048, 4, 2048, 1024, 2097152L, 131072L, 2097152L, 64L, 16, 128);
  flash_combine<1,4><<<128, blk, 0, stream>>>(
      partg, nullptr, msm_q, mss_q, gqs_hi, gqs_lo, nullptr, nullptr, 128);

  // 3) PAIR2: {kk-proj | vs-proj} merged, TM=128, A from fp32 key/value
  {
    PArg g0 = { key,   WkT_hi, kk_hi, kk_lo, 0L, 0L, 1024, 1024, 1024, 8, 128 };
    PArg g1 = { value, WvT_hi, vs_hi, vs_lo, 0L, 0L, 1024, 1024, 1024, 8, 128 };
    gemm_pair<128,0><<<2048, blk, 0, stream>>>(g0, g1, 1024, 1024);
  }

  // 4) g_scores (2-term A) -> planes; mask+scale in epilogue
  gemm_g<64,2,1,1,0><<<dim3(16,1,128), blk, 0, stream>>>(
      gqs_hi, gqs_lo, kk_hi, gsc_hi, gsc_lo, mask_ws,
      64, 64,1024,2048, 65536L,4096L, 2097152L,64L, 2097152L,131072L, 16, 2048, scale);

  // 5) gk/gv = softmax(g_scores) @ {kk,vs}  (fused dual flash, KC=4)
  flash_agg<2><<<dim3(4,128), blk, 0, stream>>>(
      gsc_hi, gsc_lo, kk_hi, kk_lo, vs_hi, vs_lo,
      part1, part2, msm_g, mss_g,
      2048, 4, 2048, 1024, 2097152L, 131072L, 2097152L, 64L, 16, 128);
  flash_combine<2,4><<<128, blk, 0, stream>>>(
      part1, part2, msm_g, mss_g, gk_hi, gk_lo, gv_hi, gv_lo, 128);

  // 6) stage 2 (MFMA): l_attn (out1) + attn hi plane
  stage2_mfma<<<dim3(16,128), blk, 0, stream>>>(qs_hi, qs_lo, gk_hi, gk_lo,
      gv_hi, gv_lo, out1, attn_hi, scale);

  // 7) out0 = attn @ Wo (TM=128, 1-term, swizzled)
  gemm_g<128,1,0,0,1><<<dim3(8,128,1), blk, 0, stream>>>(
      attn_hi, nullptr, WoT_hi, out0, nullptr, nullptr,
      1024, 1024,1024,1024, 0,0, 0,0, 0,0, 1, 2048, 1.f);

  (void)in_sizes; (void)n_in; (void)out_size; (void)ws_size;
}

// Round 15
// 511.292 us; speedup vs baseline: 1.2650x; 1.0107x over previous
//
#include <hip/hip_runtime.h>

// EGA multi-headed attention, MI355X/gfx950.
// Round 15: (a) flash_q merged INTO the kk/vs GEMM dispatch (pair_flash:
//           2048 gemm blocks + 1024 flash blocks, dynamic LDS) — absorbs the
//           serial ~35us; (b) flash split-K 4->8 with partials in virgin
//           workspace (ws_size is 512MiB; we used 276). Numerics identical.
// Dims fixed: B=8, L=S=2048, E=1024, H=16, G=64, Ek=Ev=64, KD=VD=1024.

typedef float f32x4 __attribute__((ext_vector_type(4)));
typedef _Float16 f16x8 __attribute__((ext_vector_type(8)));
typedef unsigned short u16;

#define DEV static __device__ __forceinline__

DEV u16 f2h(float x){
  _Float16 h = (_Float16)x;
  return __builtin_bit_cast(u16, h);
}
DEV float h2f(u16 u){
  return (float)__builtin_bit_cast(_Float16, u);
}
DEV void split1h(float x, u16 &h, u16 &l){
  h = f2h(x);
  l = f2h(x - h2f(h));
}
DEV unsigned pk2h(float a, float b){
  return (unsigned)f2h(a) | ((unsigned)f2h(b) << 16);
}

// async global->LDS, 16B per lane; dst is wave-uniform base (HW adds lane*16)
DEV void gload16(const u16* src, u16* dst_lds){
  __builtin_amdgcn_global_load_lds(
      (__attribute__((address_space(1))) void*)src,
      (__attribute__((address_space(3))) void*)dst_lds, 16, 0, 0);
}

// ---------------- mask dtype sniff + normalize to uchar ----------------
__global__ __launch_bounds__(256)
void mask_norm(const unsigned char* __restrict__ src, unsigned char* __restrict__ dst, int n)
{
  const unsigned* w = (const unsigned*)src;
  const int tid = threadIdx.x;
  int local = 0;
  for (int i = tid; i < n/4; i += 256){
    unsigned v = w[i];
    if (v == 0x3F800000u) local |= 2;
    else if (v > 1u)      local |= 1;
  }
  __shared__ int red[256];
  red[tid] = local;
  __syncthreads();
  for (int s = 128; s; s >>= 1){
    if (tid < s) red[tid] |= red[tid+s];
    __syncthreads();
  }
  const int r = red[0];
  const int mode = (r & 2) ? 2 : ((r & 1) ? 1 : 0);   // 2=f32, 1=u8, 0=i32
  for (int i = tid; i < n; i += 256){
    unsigned char v;
    if (mode == 1) v = src[i] ? 1 : 0;
    else           v = w[i]   ? 1 : 0;
    dst[i] = v;
  }
}

// ---------------- fp32 -> f16 hi plane (8 elems/thread) ----------------
__global__ __launch_bounds__(256)
void conv_hi(const float* __restrict__ x, u16* __restrict__ hi, int n8)
{
  const int i = blockIdx.x*256 + threadIdx.x;
  if (i >= n8) return;
  f32x4 a = ((const f32x4*)x)[2*i], b = ((const f32x4*)x)[2*i+1];
  uint4 uh;
  uh.x = pk2h(a[0], a[1]); uh.y = pk2h(a[2], a[3]);
  uh.z = pk2h(b[0], b[1]); uh.w = pk2h(b[2], b[3]);
  ((uint4*)hi)[i] = uh;
}

// ---------------- 5x 1024x1024 transpose, fp32 -> f16 hi plane (z selects) ----------------
__global__ __launch_bounds__(256)
void transpose_hi5(const float* __restrict__ s0, const float* __restrict__ s1,
                   const float* __restrict__ s2, const float* __restrict__ s3,
                   const float* __restrict__ s4,
                   u16* __restrict__ d0, u16* __restrict__ d1, u16* __restrict__ d2,
                   u16* __restrict__ d3, u16* __restrict__ d4)
{
  const int z = blockIdx.z;
  const float* Wsrc = z == 0 ? s0 : z == 1 ? s1 : z == 2 ? s2 : z == 3 ? s3 : s4;
  u16* Whi = z == 0 ? d0 : z == 1 ? d1 : z == 2 ? d2 : z == 3 ? d3 : d4;
  __shared__ float t[64][65];
  const int tid = threadIdx.x;
  const int n0 = blockIdx.x * 64, k0 = blockIdx.y * 64;
  #pragma unroll
  for (int it = 0; it < 16; ++it){
    int e = it*256 + tid, r = e >> 6, c = e & 63;
    t[r][c] = Wsrc[(long)(k0+r)*1024 + (n0+c)];
  }
  __syncthreads();
  #pragma unroll
  for (int it = 0; it < 16; ++it){
    int e = it*256 + tid, r = e >> 6, c = e & 63;
    Whi[(long)(n0+r)*1024 + (k0+c)] = f2h(t[c][r]);
  }
}

// ---------------- f16 MFMA GEMM, global_load_lds staging, dbuf (r8 loop) ----------------
template<int TM, int TERMS, int CM, int EPI, int SWZ>
__global__ __launch_bounds__(256)
void gemm_g(const u16* __restrict__ Ah_g, const u16* __restrict__ Al_g,
            const u16* __restrict__ Bh_g,
            void* __restrict__ Cp, void* __restrict__ Cp2,
            const unsigned char* __restrict__ maskp,
            int K, int lda, int ldb, int ldc,
            long aB, long aH, long bB, long bH, long cB, long cH,
            int H2, int Ssz, float scale)
{
  constexpr int BN = 128, BK = 32;
  constexpr int WM = TM/2, WN = BN/2;
  constexpr int FM = WM/16, FN = WN/16;
  __shared__ __align__(16) u16 AhS[2][TM*BK];
  __shared__ __align__(16) u16 AlS[2][TERMS == 2 ? TM*BK : 8];
  __shared__ __align__(16) u16 BhS[2][BN*BK];

  const int tid = threadIdx.x;
  int bx = blockIdx.x, by = blockIdx.y;
  if constexpr (SWZ){
    const int gx = gridDim.x;
    const int nwg = gx * gridDim.y;
    const int q = nwg >> 3;
    const int flat = bx + gx * by;
    const int nf = (flat & 7) * q + (flat >> 3);
    bx = nf % gx; by = nf / gx;
  }
  const int batch = blockIdx.z;
  const int b = batch / H2, h = batch - b*H2;
  const long aOff = (long)b*aB + (long)h*aH;
  const long bOff = (long)b*bB + (long)h*bH;
  const long cOff = (long)b*cB + (long)h*cH;
  const int nBase = bx * BN;
  const int mBase = by * TM;
  const int wave = tid >> 6, lane = tid & 63;
  const int wm = wave >> 1, wn = wave & 1;
  const int cg8 = (lane & 3) * 8;
  const int rsub = lane >> 2;

  auto stage = [&](int buf, int k0){
    #pragma unroll
    for (int c = 0; c < TM/64; ++c){
      const int chunk = wave*(TM/64) + c;
      const long g = aOff + (long)(mBase + chunk*16 + rsub)*lda + k0 + cg8;
      gload16(Ah_g + g, &AhS[buf][chunk*512]);
      if constexpr (TERMS == 2) gload16(Al_g + g, &AlS[buf][chunk*512]);
    }
    #pragma unroll
    for (int c = 0; c < 2; ++c){
      const int chunk = wave*2 + c;
      const long g = bOff + (long)(nBase + chunk*16 + rsub)*ldb + k0 + cg8;
      gload16(Bh_g + g, &BhS[buf][chunk*512]);
    }
  };

  f32x4 acc[FM][FN] = {};

  stage(0, 0);
  __syncthreads();
  const int nk = K >> 5;
  for (int t = 0; t < nk; ++t){
    const int buf = t & 1;
    if (t + 1 < nk) stage(buf ^ 1, (t + 1) << 5);

    f16x8 ah[FM], al[FM], bh[FN];
    #pragma unroll
    for (int mi = 0; mi < FM; ++mi){
      const int off = (wm*WM + mi*16 + (lane & 15))*BK + (lane >> 4)*8;
      ah[mi] = *(const f16x8*)&AhS[buf][off];
      if constexpr (TERMS == 2) al[mi] = *(const f16x8*)&AlS[buf][off];
    }
    #pragma unroll
    for (int ni = 0; ni < FN; ++ni){
      const int off = (wn*WN + ni*16 + (lane & 15))*BK + (lane >> 4)*8;
      bh[ni] = *(const f16x8*)&BhS[buf][off];
    }
    #pragma unroll
    for (int mi = 0; mi < FM; ++mi)
      #pragma unroll
      for (int ni = 0; ni < FN; ++ni){
        acc[mi][ni] = __builtin_amdgcn_mfma_f32_16x16x32_f16(ah[mi], bh[ni], acc[mi][ni], 0, 0, 0);
        if constexpr (TERMS == 2)
          acc[mi][ni] = __builtin_amdgcn_mfma_f32_16x16x32_f16(al[mi], bh[ni], acc[mi][ni], 0, 0, 0);
      }
    __syncthreads();
  }

  const int cr = (lane >> 4) * 4, cc = lane & 15;
  #pragma unroll
  for (int mi = 0; mi < FM; ++mi)
    #pragma unroll
    for (int ni = 0; ni < FN; ++ni)
      #pragma unroll
      for (int r = 0; r < 4; ++r){
        const int row = mBase + wm*WM + mi*16 + cr + r;
        const int col = nBase + wn*WN + ni*16 + cc;
        float v = acc[mi][ni][r];
        if constexpr (EPI == 1){
          v *= scale;
          if (maskp[(long)b*Ssz + col]) v = -50000.0f;
        }
        const long ci = cOff + (long)row*ldc + col;
        if constexpr (CM == 0){
          ((float*)Cp)[ci] = v;
        } else {
          u16 hh, ll;
          split1h(v, hh, ll);
          ((u16*)Cp)[ci]  = hh;
          ((u16*)Cp2)[ci] = ll;
        }
      }
}

// ---------------- merged dual-GEMM dispatch (1-term A, planes out) ----------------
struct PArg {
  const void* Ap;        // u16 plane (AMODE=1) or f32 (AMODE=0)
  const u16*  Bh;
  u16* Ch; u16* Cl;
  long bB, cB;           // z strides for B and C (A has none)
  int lda, ldb, ldc;
  int nbx, nby;
};

template<int TM, int AMODE>
__global__ __launch_bounds__(256)
void gemm_pair(PArg a0, PArg a1, int n0, int K)
{
  constexpr int BN = 128, BK = 32;
  constexpr int WM = TM/2, WN = BN/2;
  constexpr int FM = WM/16, FN = WN/16;
  constexpr int NC = TM/64;
  __shared__ __align__(16) u16 AhS[2][TM*BK];
  __shared__ __align__(16) u16 BhS[2][BN*BK];

  const int tid = threadIdx.x;
  const int gid = blockIdx.x;
  const PArg P = (gid < n0) ? a0 : a1;
  int lid = (gid < n0) ? gid : gid - n0;
  const int gsz = (gid < n0) ? n0 : ((int)gridDim.x - n0);
  {
    const int q = gsz >> 3;
    lid = (lid & 7) * q + (lid >> 3);
  }
  const int bx = lid % P.nbx;
  const int rest = lid / P.nbx;
  const int by = rest % P.nby;
  const int z  = rest / P.nby;
  const long bOff = (long)z * P.bB;
  const long cOff = (long)z * P.cB;
  const int nBase = bx * BN;
  const int mBase = by * TM;
  const int wave = tid >> 6, lane = tid & 63;
  const int wm = wave >> 1, wn = wave & 1;
  const int cg8 = (lane & 3) * 8;
  const int rsub = lane >> 2;

  const u16* Au = (const u16*)P.Ap;
  const float* Af = (const float*)P.Ap;

  auto stageB = [&](int buf, int k0){
    #pragma unroll
    for (int c = 0; c < 2; ++c){
      const int chunk = wave*2 + c;
      const long g = bOff + (long)(nBase + chunk*16 + rsub)*P.ldb + k0 + cg8;
      gload16(P.Bh + g, &BhS[buf][chunk*512]);
    }
  };
  auto stageA_g = [&](int buf, int k0){
    #pragma unroll
    for (int c = 0; c < NC; ++c){
      const int chunk = wave*NC + c;
      const long g = (long)(mBase + chunk*16 + rsub)*P.lda + k0 + cg8;
      gload16(Au + g, &AhS[buf][chunk*512]);
    }
  };

  f32x4 acc[FM][FN] = {};
  f32x4 sA0[NC], sA1[NC];

  auto loadA_f = [&](int k0){
    #pragma unroll
    for (int c = 0; c < NC; ++c){
      const int chunk = wave*NC + c;
      const long g = (long)(mBase + chunk*16 + rsub)*P.lda + k0 + cg8;
      sA0[c] = *(const f32x4*)(Af + g);
      sA1[c] = *(const f32x4*)(Af + g + 4);
    }
  };
  auto writeA_f = [&](int buf){
    #pragma unroll
    for (int c = 0; c < NC; ++c){
      const int chunk = wave*NC + c;
      uint4 u;
      u.x = pk2h(sA0[c][0], sA0[c][1]); u.y = pk2h(sA0[c][2], sA0[c][3]);
      u.z = pk2h(sA1[c][0], sA1[c][1]); u.w = pk2h(sA1[c][2], sA1[c][3]);
      *(uint4*)&AhS[buf][chunk*512 + (long)lane*8] = u;
    }
  };

  stageB(0, 0);
  if constexpr (AMODE == 1) stageA_g(0, 0);
  else { loadA_f(0); writeA_f(0); }
  __syncthreads();

  const int nk = K >> 5;
  for (int t = 0; t < nk; ++t){
    const int buf = t & 1;
    if (t + 1 < nk){
      stageB(buf ^ 1, (t + 1) << 5);
      if constexpr (AMODE == 1) stageA_g(buf ^ 1, (t + 1) << 5);
      else loadA_f((t + 1) << 5);
    }

    f16x8 ah[FM], bh[FN];
    #pragma unroll
    for (int mi = 0; mi < FM; ++mi){
      const int off = (wm*WM + mi*16 + (lane & 15))*BK + (lane >> 4)*8;
      ah[mi] = *(const f16x8*)&AhS[buf][off];
    }
    #pragma unroll
    for (int ni = 0; ni < FN; ++ni){
      const int off = (wn*WN + ni*16 + (lane & 15))*BK + (lane >> 4)*8;
      bh[ni] = *(const f16x8*)&BhS[buf][off];
    }
    #pragma unroll
    for (int mi = 0; mi < FM; ++mi)
      #pragma unroll
      for (int ni = 0; ni < FN; ++ni)
        acc[mi][ni] = __builtin_amdgcn_mfma_f32_16x16x32_f16(ah[mi], bh[ni], acc[mi][ni], 0, 0, 0);

    if constexpr (AMODE == 0){
      if (t + 1 < nk) writeA_f(buf ^ 1);
    }
    __syncthreads();
  }

  const int cr = (lane >> 4) * 4, cc = lane & 15;
  #pragma unroll
  for (int mi = 0; mi < FM; ++mi)
    #pragma unroll
    for (int ni = 0; ni < FN; ++ni)
      #pragma unroll
      for (int r = 0; r < 4; ++r){
        const int row = mBase + wm*WM + mi*16 + cr + r;
        const int col = nBase + wn*WN + ni*16 + cc;
        const long ci = cOff + (long)row*P.ldc + col;
        u16 hh, ll;
        split1h(acc[mi][ni][r], hh, ll);
        P.Ch[ci] = hh;
        P.Cl[ci] = ll;
      }
}

// ---------------- device body: 128x128 GEMM, A=fp32 reg-staged (dynamic LDS) ----------------
DEV void dev_gemm_f32A(const PArg P, int lid, int tid, char* sm, int K)
{
  constexpr int BK = 32;
  constexpr int FM = 4, FN = 4, NC = 2;   // TM=128, BN=128, WM=WN=64
  u16* AhS = (u16*)sm;                    // [2][4096]
  u16* BhS = (u16*)(sm + 16384);          // [2][4096]

  const int bx = lid % P.nbx;
  const int rest = lid / P.nbx;
  const int by = rest % P.nby;
  const int z  = rest / P.nby;
  const long bOff = (long)z * P.bB;
  const long cOff = (long)z * P.cB;
  const int nBase = bx * 128;
  const int mBase = by * 128;
  const int wave = tid >> 6, lane = tid & 63;
  const int wm = wave >> 1, wn = wave & 1;
  const int cg8 = (lane & 3) * 8;
  const int rsub = lane >> 2;

  const float* Af = (const float*)P.Ap;

  auto stageB = [&](int buf, int k0){
    #pragma unroll
    for (int c = 0; c < 2; ++c){
      const int chunk = wave*2 + c;
      const long g = bOff + (long)(nBase + chunk*16 + rsub)*P.ldb + k0 + cg8;
      gload16(P.Bh + g, &BhS[buf*4096 + chunk*512]);
    }
  };

  f32x4 acc[FM][FN] = {};
  f32x4 sA0[NC], sA1[NC];

  auto loadA_f = [&](int k0){
    #pragma unroll
    for (int c = 0; c < NC; ++c){
      const int chunk = wave*NC + c;
      const long g = (long)(mBase + chunk*16 + rsub)*P.lda + k0 + cg8;
      sA0[c] = *(const f32x4*)(Af + g);
      sA1[c] = *(const f32x4*)(Af + g + 4);
    }
  };
  auto writeA_f = [&](int buf){
    #pragma unroll
    for (int c = 0; c < NC; ++c){
      const int chunk = wave*NC + c;
      uint4 u;
      u.x = pk2h(sA0[c][0], sA0[c][1]); u.y = pk2h(sA0[c][2], sA0[c][3]);
      u.z = pk2h(sA1[c][0], sA1[c][1]); u.w = pk2h(sA1[c][2], sA1[c][3]);
      *(uint4*)&AhS[buf*4096 + chunk*512 + lane*8] = u;
    }
  };

  stageB(0, 0);
  loadA_f(0); writeA_f(0);
  __syncthreads();

  const int nk = K >> 5;
  for (int t = 0; t < nk; ++t){
    const int buf = t & 1;
    if (t + 1 < nk){
      stageB(buf ^ 1, (t + 1) << 5);
      loadA_f((t + 1) << 5);
    }

    f16x8 ah[FM], bh[FN];
    #pragma unroll
    for (int mi = 0; mi < FM; ++mi){
      const int off = (wm*64 + mi*16 + (lane & 15))*BK + (lane >> 4)*8;
      ah[mi] = *(const f16x8*)&AhS[buf*4096 + off];
    }
    #pragma unroll
    for (int ni = 0; ni < FN; ++ni){
      const int off = (wn*64 + ni*16 + (lane & 15))*BK + (lane >> 4)*8;
      bh[ni] = *(const f16x8*)&BhS[buf*4096 + off];
    }
    #pragma unroll
    for (int mi = 0; mi < FM; ++mi)
      #pragma unroll
      for (int ni = 0; ni < FN; ++ni)
        acc[mi][ni] = __builtin_amdgcn_mfma_f32_16x16x32_f16(ah[mi], bh[ni], acc[mi][ni], 0, 0, 0);

    if (t + 1 < nk) writeA_f(buf ^ 1);
    __syncthreads();
  }

  const int cr = (lane >> 4) * 4, cc = lane & 15;
  #pragma unroll
  for (int mi = 0; mi < FM; ++mi)
    #pragma unroll
    for (int ni = 0; ni < FN; ++ni)
      #pragma unroll
      for (int r = 0; r < 4; ++r){
        const int row = mBase + wm*64 + mi*16 + cr + r;
        const int col = nBase + wn*64 + ni*16 + cc;
        const long ci = cOff + (long)row*P.ldc + col;
        u16 hh, ll;
        split1h(acc[mi][ni][r], hh, ll);
        P.Ch[ci] = hh;
        P.Cl[ci] = ll;
      }
}

// ---------------- device body: flash aggregation NB=1 (dynamic LDS) ----------------
DEV void dev_flash1(const u16* Sh_g, const u16* Sl_g,
                    const u16* B1h_g, const u16* B1l_g,
                    float* P1, float* msm, float* mss,
                    int kc, int batch, int tid, char* sm,
                    int K, int KC, int lda, int ldb,
                    long aB, long aH, long bB, long bH, int H2, int nbatch)
{
  u16 (*Ph)[72]   = (u16(*)[72])(sm);
  u16 (*Pl)[72]   = (u16(*)[72])(sm + 9216);
  u16 (*B1hS)[72] = (u16(*)[72])(sm + 18432);
  u16 (*B1lS)[72] = (u16(*)[72])(sm + 27648);
  float* mS = (float*)(sm + 36864);
  float* sS = (float*)(sm + 37120);
  float* fS = (float*)(sm + 37376);

  const int b = batch / H2, h = batch - b*H2;
  const long aOff = (long)b*aB + (long)h*aH;
  const long bOff = (long)b*bB + (long)h*bH;
  const int kchunk = K / KC, kbeg = kc * kchunk;
  const int wm = tid >> 6, lane = tid & 63;
  const int srow = tid >> 2, sq = tid & 3;

  if (tid < 64){ mS[tid] = -1e30f; sS[tid] = 0.f; }

  f32x4 acc1[4] = {};

  for (int ks = kbeg; ks < kbeg + kchunk; ks += 64){
    __syncthreads();
    #pragma unroll
    for (int it = 0; it < 4; ++it){
      const int e = it*256 + tid;
      const int lr = e >> 4, d0 = (e & 15) * 4;
      const long gm = bOff + (long)(ks + lr)*ldb + d0;
      ushort4 h4 = *(const ushort4*)(B1h_g + gm);
      ushort4 l4 = *(const ushort4*)(B1l_g + gm);
      B1hS[d0+0][lr]=h4.x; B1hS[d0+1][lr]=h4.y; B1hS[d0+2][lr]=h4.z; B1hS[d0+3][lr]=h4.w;
      B1lS[d0+0][lr]=l4.x; B1lS[d0+1][lr]=l4.y; B1lS[d0+2][lr]=l4.z; B1lS[d0+3][lr]=l4.w;
    }

    float v[16];
    {
      const long ga = aOff + (long)srow*lda + ks + sq*16;
      uint4 ha = *(const uint4*)(Sh_g + ga);
      uint4 hb = *(const uint4*)(Sh_g + ga + 8);
      uint4 la = *(const uint4*)(Sl_g + ga);
      uint4 lb = *(const uint4*)(Sl_g + ga + 8);
      v[0]=h2f((u16)ha.x)+h2f((u16)la.x);  v[1]=h2f((u16)(ha.x>>16))+h2f((u16)(la.x>>16));
      v[2]=h2f((u16)ha.y)+h2f((u16)la.y);  v[3]=h2f((u16)(ha.y>>16))+h2f((u16)(la.y>>16));
      v[4]=h2f((u16)ha.z)+h2f((u16)la.z);  v[5]=h2f((u16)(ha.z>>16))+h2f((u16)(la.z>>16));
      v[6]=h2f((u16)ha.w)+h2f((u16)la.w);  v[7]=h2f((u16)(ha.w>>16))+h2f((u16)(la.w>>16));
      v[8]=h2f((u16)hb.x)+h2f((u16)lb.x);  v[9]=h2f((u16)(hb.x>>16))+h2f((u16)(lb.x>>16));
      v[10]=h2f((u16)hb.y)+h2f((u16)lb.y); v[11]=h2f((u16)(hb.y>>16))+h2f((u16)(lb.y>>16));
      v[12]=h2f((u16)hb.z)+h2f((u16)lb.z); v[13]=h2f((u16)(hb.z>>16))+h2f((u16)(lb.z>>16));
      v[14]=h2f((u16)hb.w)+h2f((u16)lb.w); v[15]=h2f((u16)(hb.w>>16))+h2f((u16)(lb.w>>16));
    }
    float mx = v[0];
    #pragma unroll
    for (int i = 1; i < 16; ++i) mx = fmaxf(mx, v[i]);
    mx = fmaxf(mx, __shfl_xor(mx, 1));
    mx = fmaxf(mx, __shfl_xor(mx, 2));
    const float mold = mS[srow];
    const float mnew = fmaxf(mold, mx);
    float sum = 0.f;
    u16 ph[16], pl[16];
    #pragma unroll
    for (int i = 0; i < 16; ++i){
      float e = __expf(v[i] - mnew);
      sum += e;
      split1h(e, ph[i], pl[i]);
    }
    sum += __shfl_xor(sum, 1);
    sum += __shfl_xor(sum, 2);
    if (sq == 0){
      const float f = __expf(mold - mnew);
      sS[srow] = sS[srow] * f + sum;
      mS[srow] = mnew;
      fS[srow] = f;
    }
    {
      uint4 uh0, uh1, ul0, ul1;
      uh0.x=(unsigned)ph[0]|((unsigned)ph[1]<<16);  uh0.y=(unsigned)ph[2]|((unsigned)ph[3]<<16);
      uh0.z=(unsigned)ph[4]|((unsigned)ph[5]<<16);  uh0.w=(unsigned)ph[6]|((unsigned)ph[7]<<16);
      uh1.x=(unsigned)ph[8]|((unsigned)ph[9]<<16);  uh1.y=(unsigned)ph[10]|((unsigned)ph[11]<<16);
      uh1.z=(unsigned)ph[12]|((unsigned)ph[13]<<16);uh1.w=(unsigned)ph[14]|((unsigned)ph[15]<<16);
      ul0.x=(unsigned)pl[0]|((unsigned)pl[1]<<16);  ul0.y=(unsigned)pl[2]|((unsigned)pl[3]<<16);
      ul0.z=(unsigned)pl[4]|((unsigned)pl[5]<<16);  ul0.w=(unsigned)pl[6]|((unsigned)pl[7]<<16);
      ul1.x=(unsigned)pl[8]|((unsigned)pl[9]<<16);  ul1.y=(unsigned)pl[10]|((unsigned)pl[11]<<16);
      ul1.z=(unsigned)pl[12]|((unsigned)pl[13]<<16);ul1.w=(unsigned)pl[14]|((unsigned)pl[15]<<16);
      *(uint4*)&Ph[srow][sq*16]     = uh0;
      *(uint4*)&Ph[srow][sq*16 + 8] = uh1;
      *(uint4*)&Pl[srow][sq*16]     = ul0;
      *(uint4*)&Pl[srow][sq*16 + 8] = ul1;
    }
    __syncthreads();

    float fr4[4];
    #pragma unroll
    for (int r = 0; r < 4; ++r) fr4[r] = fS[wm*16 + (lane >> 4)*4 + r];
    #pragma unroll
    for (int ni = 0; ni < 4; ++ni)
      #pragma unroll
      for (int r = 0; r < 4; ++r)
        acc1[ni][r] *= fr4[r];
    #pragma unroll
    for (int k0 = 0; k0 < 64; k0 += 32){
      const int ko = k0 + (lane >> 4)*8;
      const int fr = lane & 15;
      f16x8 a_h = *(const f16x8*)&Ph[wm*16 + fr][ko];
      f16x8 a_l = *(const f16x8*)&Pl[wm*16 + fr][ko];
      #pragma unroll
      for (int ni = 0; ni < 4; ++ni){
        f16x8 b_h = *(const f16x8*)&B1hS[ni*16 + fr][ko];
        f16x8 b_l = *(const f16x8*)&B1lS[ni*16 + fr][ko];
        acc1[ni] = __builtin_amdgcn_mfma_f32_16x16x32_f16(a_h, b_h, acc1[ni], 0, 0, 0);
        acc1[ni] = __builtin_amdgcn_mfma_f32_16x16x32_f16(a_l, b_h, acc1[ni], 0, 0, 0);
        acc1[ni] = __builtin_amdgcn_mfma_f32_16x16x32_f16(a_h, b_l, acc1[ni], 0, 0, 0);
      }
    }
  }

  const long po = ((long)(kc*nbatch + batch) << 12);
  const int cr = (lane >> 4) * 4, cc = lane & 15;
  #pragma unroll
  for (int ni = 0; ni < 4; ++ni)
    #pragma unroll
    for (int r = 0; r < 4; ++r){
      const int g = wm*16 + cr + r, d = ni*16 + cc;
      P1[po + g*64 + d] = acc1[ni][r];
    }
  if (tid < 64){
    msm[((long)kc*nbatch + batch)*64 + tid] = mS[tid];
    mss[((long)kc*nbatch + batch)*64 + tid] = sS[tid];
  }
}

// ---------------- merged dispatch: {kk,vs} GEMMs + flash_q (KC=8) ----------------
__global__ __launch_bounds__(256)
void pair_flash(PArg a0, PArg a1,
                const u16* Sh, const u16* Sl, const u16* B1h, const u16* B1l,
                float* P1, float* msm, float* mss, int K)
{
  extern __shared__ char smdyn[];
  const int gid = blockIdx.x;
  const int tid = threadIdx.x;
  if (gid < 2048){
    const PArg P = (gid < 1024) ? a0 : a1;
    int lid = (gid < 1024) ? gid : gid - 1024;
    lid = (lid & 7) * 128 + (lid >> 3);     // bijective XCD swizzle (1024 % 8 == 0)
    dev_gemm_f32A(P, lid, tid, smdyn, K);
  } else {
    const int l2 = gid - 2048;              // 1024 flash blocks: kc in [0,8), batch in [0,128)
    dev_flash1(Sh, Sl, B1h, B1l, P1, msm, mss,
               l2 >> 7, l2 & 127, tid, smdyn,
               2048, 8, 2048, 1024, 2097152L, 131072L, 2097152L, 64L, 16, 128);
  }
}

// ---------------- flash aggregation v2 (standalone, dual) ----------------
template<int NB>
__global__ __launch_bounds__(256)
void flash_agg(const u16* __restrict__ Sh_g, const u16* __restrict__ Sl_g,
               const u16* __restrict__ B1h_g, const u16* __restrict__ B1l_g,
               const u16* __restrict__ B2h_g, const u16* __restrict__ B2l_g,
               float* __restrict__ P1, float* __restrict__ P2,
               float* __restrict__ msm, float* __restrict__ mss,
               int K, int KC, int lda, int ldb,
               long aB, long aH, long bB, long bH, int H2, int nbatch)
{
  __shared__ __align__(16) u16 Ph[64][72], Pl[64][72];
  __shared__ __align__(16) u16 B1hS[64][72], B1lS[64][72];
  __shared__ __align__(16) u16 B2hS[NB==2?64:1][72], B2lS[NB==2?64:1][72];
  __shared__ float mS[64], sS[64], fS[64];
  const int tid = threadIdx.x;
  const int kc = blockIdx.x, batch = blockIdx.y;
  const int b = batch / H2, h = batch - b*H2;
  const long aOff = (long)b*aB + (long)h*aH;
  const long bOff = (long)b*bB + (long)h*bH;
  const int kchunk = K / KC, kbeg = kc * kchunk;
  const int wm = tid >> 6, lane = tid & 63;
  const int srow = tid >> 2, sq = tid & 3;

  if (tid < 64){ mS[tid] = -1e30f; sS[tid] = 0.f; }

  f32x4 acc1[4] = {}, acc2[4] = {};

  for (int ks = kbeg; ks < kbeg + kchunk; ks += 64){
    __syncthreads();
    #pragma unroll
    for (int it = 0; it < 4; ++it){
      const int e = it*256 + tid;
      const int lr = e >> 4, d0 = (e & 15) * 4;
      const long gm = bOff + (long)(ks + lr)*ldb + d0;
      ushort4 h4 = *(const ushort4*)(B1h_g + gm);
      ushort4 l4 = *(const ushort4*)(B1l_g + gm);
      B1hS[d0+0][lr]=h4.x; B1hS[d0+1][lr]=h4.y; B1hS[d0+2][lr]=h4.z; B1hS[d0+3][lr]=h4.w;
      B1lS[d0+0][lr]=l4.x; B1lS[d0+1][lr]=l4.y; B1lS[d0+2][lr]=l4.z; B1lS[d0+3][lr]=l4.w;
      if constexpr (NB == 2){
        ushort4 h42 = *(const ushort4*)(B2h_g + gm);
        ushort4 l42 = *(const ushort4*)(B2l_g + gm);
        B2hS[d0+0][lr]=h42.x; B2hS[d0+1][lr]=h42.y; B2hS[d0+2][lr]=h42.z; B2hS[d0+3][lr]=h42.w;
        B2lS[d0+0][lr]=l42.x; B2lS[d0+1][lr]=l42.y; B2lS[d0+2][lr]=l42.z; B2lS[d0+3][lr]=l42.w;
      }
    }

    float v[16];
    {
      const long ga = aOff + (long)srow*lda + ks + sq*16;
      uint4 ha = *(const uint4*)(Sh_g + ga);
      uint4 hb = *(const uint4*)(Sh_g + ga + 8);
      uint4 la = *(const uint4*)(Sl_g + ga);
      uint4 lb = *(const uint4*)(Sl_g + ga + 8);
      v[0]=h2f((u16)ha.x)+h2f((u16)la.x);  v[1]=h2f((u16)(ha.x>>16))+h2f((u16)(la.x>>16));
      v[2]=h2f((u16)ha.y)+h2f((u16)la.y);  v[3]=h2f((u16)(ha.y>>16))+h2f((u16)(la.y>>16));
      v[4]=h2f((u16)ha.z)+h2f((u16)la.z);  v[5]=h2f((u16)(ha.z>>16))+h2f((u16)(la.z>>16));
      v[6]=h2f((u16)ha.w)+h2f((u16)la.w);  v[7]=h2f((u16)(ha.w>>16))+h2f((u16)(la.w>>16));
      v[8]=h2f((u16)hb.x)+h2f((u16)lb.x);  v[9]=h2f((u16)(hb.x>>16))+h2f((u16)(lb.x>>16));
      v[10]=h2f((u16)hb.y)+h2f((u16)lb.y); v[11]=h2f((u16)(hb.y>>16))+h2f((u16)(lb.y>>16));
      v[12]=h2f((u16)hb.z)+h2f((u16)lb.z); v[13]=h2f((u16)(hb.z>>16))+h2f((u16)(lb.z>>16));
      v[14]=h2f((u16)hb.w)+h2f((u16)lb.w); v[15]=h2f((u16)(hb.w>>16))+h2f((u16)(lb.w>>16));
    }
    float mx = v[0];
    #pragma unroll
    for (int i = 1; i < 16; ++i) mx = fmaxf(mx, v[i]);
    mx = fmaxf(mx, __shfl_xor(mx, 1));
    mx = fmaxf(mx, __shfl_xor(mx, 2));
    const float mold = mS[srow];
    const float mnew = fmaxf(mold, mx);
    float sum = 0.f;
    u16 ph[16], pl[16];
    #pragma unroll
    for (int i = 0; i < 16; ++i){
      float e = __expf(v[i] - mnew);
      sum += e;
      split1h(e, ph[i], pl[i]);
    }
    sum += __shfl_xor(sum, 1);
    sum += __shfl_xor(sum, 2);
    if (sq == 0){
      const float f = __expf(mold - mnew);
      sS[srow] = sS[srow] * f + sum;
      mS[srow] = mnew;
      fS[srow] = f;
    }
    {
      uint4 uh0, uh1, ul0, ul1;
      uh0.x=(unsigned)ph[0]|((unsigned)ph[1]<<16);  uh0.y=(unsigned)ph[2]|((unsigned)ph[3]<<16);
      uh0.z=(unsigned)ph[4]|((unsigned)ph[5]<<16);  uh0.w=(unsigned)ph[6]|((unsigned)ph[7]<<16);
      uh1.x=(unsigned)ph[8]|((unsigned)ph[9]<<16);  uh1.y=(unsigned)ph[10]|((unsigned)ph[11]<<16);
      uh1.z=(unsigned)ph[12]|((unsigned)ph[13]<<16);uh1.w=(unsigned)ph[14]|((unsigned)ph[15]<<16);
      ul0.x=(unsigned)pl[0]|((unsigned)pl[1]<<16);  ul0.y=(unsigned)pl[2]|((unsigned)pl[3]<<16);
      ul0.z=(unsigned)pl[4]|((unsigned)pl[5]<<16);  ul0.w=(unsigned)pl[6]|((unsigned)pl[7]<<16);
      ul1.x=(unsigned)pl[8]|((unsigned)pl[9]<<16);  ul1.y=(unsigned)pl[10]|((unsigned)pl[11]<<16);
      ul1.z=(unsigned)pl[12]|((unsigned)pl[13]<<16);ul1.w=(unsigned)pl[14]|((unsigned)pl[15]<<16);
      *(uint4*)&Ph[srow][sq*16]     = uh0;
      *(uint4*)&Ph[srow][sq*16 + 8] = uh1;
      *(uint4*)&Pl[srow][sq*16]     = ul0;
      *(uint4*)&Pl[srow][sq*16 + 8] = ul1;
    }
    __syncthreads();

    float fr4[4];
    #pragma unroll
    for (int r = 0; r < 4; ++r) fr4[r] = fS[wm*16 + (lane >> 4)*4 + r];
    #pragma unroll
    for (int ni = 0; ni < 4; ++ni)
      #pragma unroll
      for (int r = 0; r < 4; ++r){
        acc1[ni][r] *= fr4[r];
        if constexpr (NB == 2) acc2[ni][r] *= fr4[r];
      }
    #pragma unroll
    for (int k0 = 0; k0 < 64; k0 += 32){
      const int ko = k0 + (lane >> 4)*8;
      const int fr = lane & 15;
      f16x8 a_h = *(const f16x8*)&Ph[wm*16 + fr][ko];
      f16x8 a_l = *(const f16x8*)&Pl[wm*16 + fr][ko];
      #pragma unroll
      for (int ni = 0; ni < 4; ++ni){
        f16x8 b_h = *(const f16x8*)&B1hS[ni*16 + fr][ko];
        f16x8 b_l = *(const f16x8*)&B1lS[ni*16 + fr][ko];
        acc1[ni] = __builtin_amdgcn_mfma_f32_16x16x32_f16(a_h, b_h, acc1[ni], 0, 0, 0);
        acc1[ni] = __builtin_amdgcn_mfma_f32_16x16x32_f16(a_l, b_h, acc1[ni], 0, 0, 0);
        acc1[ni] = __builtin_amdgcn_mfma_f32_16x16x32_f16(a_h, b_l, acc1[ni], 0, 0, 0);
        if constexpr (NB == 2){
          f16x8 c_h = *(const f16x8*)&B2hS[ni*16 + fr][ko];
          f16x8 c_l = *(const f16x8*)&B2lS[ni*16 + fr][ko];
          acc2[ni] = __builtin_amdgcn_mfma_f32_16x16x32_f16(a_h, c_h, acc2[ni], 0, 0, 0);
          acc2[ni] = __builtin_amdgcn_mfma_f32_16x16x32_f16(a_l, c_h, acc2[ni], 0, 0, 0);
          acc2[ni] = __builtin_amdgcn_mfma_f32_16x16x32_f16(a_h, c_l, acc2[ni], 0, 0, 0);
        }
      }
    }
  }

  const long po = ((long)(kc*nbatch + batch) << 12);
  const int cr = (lane >> 4) * 4, cc = lane & 15;
  #pragma unroll
  for (int ni = 0; ni < 4; ++ni)
    #pragma unroll
    for (int r = 0; r < 4; ++r){
      const int g = wm*16 + cr + r, d = ni*16 + cc;
      P1[po + g*64 + d] = acc1[ni][r];
      if constexpr (NB == 2) P2[po + g*64 + d] = acc2[ni][r];
    }
  if (tid < 64){
    msm[((long)kc*nbatch + batch)*64 + tid] = mS[tid];
    mss[((long)kc*nbatch + batch)*64 + tid] = sS[tid];
  }
}

// ---------------- exact cross-chunk combine (compile-time KC) ----------------
template<int NB, int KC>
__global__ __launch_bounds__(256)
void flash_combine(const float* __restrict__ P1, const float* __restrict__ P2,
                   const float* __restrict__ msm, const float* __restrict__ mss,
                   u16* __restrict__ o1h, u16* __restrict__ o1l,
                   u16* __restrict__ o2h, u16* __restrict__ o2l, int nbatch)
{
  const int batch = blockIdx.x;
  const int tid = threadIdx.x;
  const int g = tid >> 2, dq = (tid & 3) * 16;
  float m[KC], s[KC], w[KC];
  float M = -1e30f;
  #pragma unroll
  for (int c = 0; c < KC; ++c){
    m[c] = msm[((long)c*nbatch + batch)*64 + g];
    s[c] = mss[((long)c*nbatch + batch)*64 + g];
    M = fmaxf(M, m[c]);
  }
  float den = 0.f;
  #pragma unroll
  for (int c = 0; c < KC; ++c){ w[c] = __expf(m[c] - M); den += s[c]*w[c]; }
  const float inv = 1.0f / den;
  #pragma unroll
  for (int c = 0; c < KC; ++c) w[c] *= inv;
  const long oo = (long)batch*4096 + g*64 + dq;
  #pragma unroll
  for (int nb = 0; nb < NB; ++nb){
    const float* Pa = nb ? P2 : P1;
    u16* oh = nb ? o2h : o1h;
    u16* ol = nb ? o2l : o1l;
    u16 hh[16], ll[16];
    #pragma unroll
    for (int j = 0; j < 4; ++j){
      f32x4 a = {0.f, 0.f, 0.f, 0.f};
      #pragma unroll
      for (int c = 0; c < KC; ++c){
        f32x4 p = *(const f32x4*)(Pa + (((long)c*nbatch + batch) << 12) + g*64 + dq + j*4);
        a += p * w[c];
      }
      #pragma unroll
      for (int e = 0; e < 4; ++e) split1h(a[e], hh[j*4+e], ll[j*4+e]);
    }
    uint4 uh0, uh1, ul0, ul1;
    uh0.x=(unsigned)hh[0]|((unsigned)hh[1]<<16);  uh0.y=(unsigned)hh[2]|((unsigned)hh[3]<<16);
    uh0.z=(unsigned)hh[4]|((unsigned)hh[5]<<16);  uh0.w=(unsigned)hh[6]|((unsigned)hh[7]<<16);
    uh1.x=(unsigned)hh[8]|((unsigned)hh[9]<<16);  uh1.y=(unsigned)hh[10]|((unsigned)hh[11]<<16);
    uh1.z=(unsigned)hh[12]|((unsigned)hh[13]<<16);uh1.w=(unsigned)hh[14]|((unsigned)hh[15]<<16);
    ul0.x=(unsigned)ll[0]|((unsigned)ll[1]<<16);  ul0.y=(unsigned)ll[2]|((unsigned)ll[3]<<16);
    ul0.z=(unsigned)ll[4]|((unsigned)ll[5]<<16);  ul0.w=(unsigned)ll[6]|((unsigned)ll[7]<<16);
    ul1.x=(unsigned)ll[8]|((unsigned)ll[9]<<16);  ul1.y=(unsigned)ll[10]|((unsigned)ll[11]<<16);
    ul1.z=(unsigned)ll[12]|((unsigned)ll[13]<<16);ul1.w=(unsigned)ll[14]|((unsigned)ll[15]<<16);
    *(uint4*)(oh + oo)     = uh0;
    *(uint4*)(oh + oo + 8) = uh1;
    *(uint4*)(ol + oo)     = ul0;
    *(uint4*)(ol + oo + 8) = ul1;
  }
}

// ---------------- stage 2, MFMA ----------------
__global__ __launch_bounds__(256)
void stage2_mfma(const u16* __restrict__ qhi, const u16* __restrict__ qlo,
                 const u16* __restrict__ gkh_g, const u16* __restrict__ gkl_g,
                 const u16* __restrict__ gvh_g, const u16* __restrict__ gvl_g,
                 float* __restrict__ lattn, u16* __restrict__ ahi,
                 float scale)
{
  __shared__ __align__(16) u16 Ah[128][72];
  __shared__ __align__(16) u16 Al[128][72];
  __shared__ __align__(16) u16 Bh[64][72];
  __shared__ __align__(16) u16 Bl[64][72];
  const int tid = threadIdx.x;
  const int bh = blockIdx.y;
  const int b = bh >> 4, h = bh & 15;
  const int l0 = blockIdx.x * 128;
  const int wm = tid >> 6, lane = tid & 63;

  const long qbase = ((long)b*2048 + l0)*1024 + h*64;
  #pragma unroll
  for (int it = 0; it < 4; ++it){
    const int e = it*256 + tid, row = e >> 3, s = e & 7;
    const long g = qbase + (long)row*1024 + s*8;
    *(uint4*)&Ah[row][s*8] = *(const uint4*)(qhi + g);
    *(uint4*)&Al[row][s*8] = *(const uint4*)(qlo + g);
  }
  const long gb = (long)bh * 4096;
  #pragma unroll
  for (int it = 0; it < 2; ++it){
    const int e = it*256 + tid, gr = e >> 3, s = e & 7;
    *(uint4*)&Bh[gr][s*8] = *(const uint4*)(gkh_g + gb + gr*64 + s*8);
    *(uint4*)&Bl[gr][s*8] = *(const uint4*)(gkl_g + gb + gr*64 + s*8);
  }
  __syncthreads();

  f32x4 acc[2][4] = {};
  #pragma unroll
  for (int k0 = 0; k0 < 64; k0 += 32){
    f16x8 a_h[2], a_l[2], b_h[4], b_l[4];
    #pragma unroll
    for (int mi = 0; mi < 2; ++mi){
      const int row = wm*32 + mi*16 + (lane & 15);
      a_h[mi] = *(const f16x8*)&Ah[row][k0 + (lane >> 4)*8];
      a_l[mi] = *(const f16x8*)&Al[row][k0 + (lane >> 4)*8];
    }
    #pragma unroll
    for (int ni = 0; ni < 4; ++ni){
      const int nr = ni*16 + (lane & 15);
      b_h[ni] = *(const f16x8*)&Bh[nr][k0 + (lane >> 4)*8];
      b_l[ni] = *(const f16x8*)&Bl[nr][k0 + (lane >> 4)*8];
    }
    #pragma unroll
    for (int mi = 0; mi < 2; ++mi)
      #pragma unroll
      for (int ni = 0; ni < 4; ++ni){
        acc[mi][ni] = __builtin_amdgcn_mfma_f32_16x16x32_f16(a_h[mi], b_h[ni], acc[mi][ni], 0, 0, 0);
        acc[mi][ni] = __builtin_amdgcn_mfma_f32_16x16x32_f16(a_l[mi], b_h[ni], acc[mi][ni], 0, 0, 0);
        acc[mi][ni] = __builtin_amdgcn_mfma_f32_16x16x32_f16(a_h[mi], b_l[ni], acc[mi][ni], 0, 0, 0);
      }
  }
  __syncthreads();

  #pragma unroll
  for (int it = 0; it < 4; ++it){
    const int e = it*256 + tid;
    const int gr = e >> 4, d0 = (e & 15) * 4;
    ushort4 vh = *(const ushort4*)(gvh_g + gb + gr*64 + d0);
    ushort4 vl = *(const ushort4*)(gvl_g + gb + gr*64 + d0);
    Bh[d0+0][gr] = vh.x; Bh[d0+1][gr] = vh.y; Bh[d0+2][gr] = vh.z; Bh[d0+3][gr] = vh.w;
    Bl[d0+0][gr] = vl.x; Bl[d0+1][gr] = vl.y; Bl[d0+2][gr] = vl.z; Bl[d0+3][gr] = vl.w;
  }

  #pragma unroll
  for (int mi = 0; mi < 2; ++mi){
    #pragma unroll
    for (int r = 0; r < 4; ++r){
      float v0 = acc[mi][0][r]*scale, v1 = acc[mi][1][r]*scale;
      float v2 = acc[mi][2][r]*scale, v3 = acc[mi][3][r]*scale;
      float mx = fmaxf(fmaxf(v0,v1), fmaxf(v2,v3));
      #pragma unroll
      for (int off = 1; off < 16; off <<= 1) mx = fmaxf(mx, __shfl_xor(mx, off, 16));
      float e0 = __expf(v0-mx), e1 = __expf(v1-mx), e2 = __expf(v2-mx), e3 = __expf(v3-mx);
      float sum = (e0+e1) + (e2+e3);
      #pragma unroll
      for (int off = 1; off < 16; off <<= 1) sum += __shfl_xor(sum, off, 16);
      const float inv = 1.0f / sum;
      e0 *= inv; e1 *= inv; e2 *= inv; e3 *= inv;
      const int lrow = wm*32 + mi*16 + (lane >> 4)*4 + r;
      float* lp = lattn + ((long)bh*2048 + l0 + lrow)*64 + (lane & 15);
      lp[0] = e0; lp[16] = e1; lp[32] = e2; lp[48] = e3;
      u16 hh, ll;
      split1h(e0, hh, ll); Ah[lrow][ 0 + (lane&15)] = hh; Al[lrow][ 0 + (lane&15)] = ll;
      split1h(e1, hh, ll); Ah[lrow][16 + (lane&15)] = hh; Al[lrow][16 + (lane&15)] = ll;
      split1h(e2, hh, ll); Ah[lrow][32 + (lane&15)] = hh; Al[lrow][32 + (lane&15)] = ll;
      split1h(e3, hh, ll); Ah[lrow][48 + (lane&15)] = hh; Al[lrow][48 + (lane&15)] = ll;
    }
  }
  __syncthreads();

  f32x4 o[2][4] = {};
  #pragma unroll
  for (int k0 = 0; k0 < 64; k0 += 32){
    f16x8 p_h[2], p_l[2], b_h[4], b_l[4];
    #pragma unroll
    for (int mi = 0; mi < 2; ++mi){
      const int row = wm*32 + mi*16 + (lane & 15);
      p_h[mi] = *(const f16x8*)&Ah[row][k0 + (lane >> 4)*8];
      p_l[mi] = *(const f16x8*)&Al[row][k0 + (lane >> 4)*8];
    }
    #pragma unroll
    for (int ni = 0; ni < 4; ++ni){
      const int nr = ni*16 + (lane & 15);
      b_h[ni] = *(const f16x8*)&Bh[nr][k0 + (lane >> 4)*8];
      b_l[ni] = *(const f16x8*)&Bl[nr][k0 + (lane >> 4)*8];
    }
    #pragma unroll
    for (int mi = 0; mi < 2; ++mi)
      #pragma unroll
      for (int ni = 0; ni < 4; ++ni){
        o[mi][ni] = __builtin_amdgcn_mfma_f32_16x16x32_f16(p_h[mi], b_h[ni], o[mi][ni], 0, 0, 0);
        o[mi][ni] = __builtin_amdgcn_mfma_f32_16x16x32_f16(p_l[mi], b_h[ni], o[mi][ni], 0, 0, 0);
        o[mi][ni] = __builtin_amdgcn_mfma_f32_16x16x32_f16(p_h[mi], b_l[ni], o[mi][ni], 0, 0, 0);
      }
  }

  #pragma unroll
  for (int mi = 0; mi < 2; ++mi)
    #pragma unroll
    for (int ni = 0; ni < 4; ++ni)
      #pragma unroll
      for (int r = 0; r < 4; ++r){
        const int lrow = wm*32 + mi*16 + (lane >> 4)*4 + r;
        const int d = ni*16 + (lane & 15);
        const long oidx = ((long)b*2048 + l0 + lrow)*1024 + h*64 + d;
        ahi[oidx] = f2h(o[mi][ni][r]);
      }
}

extern "C" void kernel_launch(void* const* d_in, const int* in_sizes, int n_in,
                              void* d_out, int out_size, void* d_ws, size_t ws_size,
                              hipStream_t stream)
{
  const float* query = (const float*)d_in[0];
  const float* key   = (const float*)d_in[1];
  const float* value = (const float*)d_in[2];
  const unsigned char* mask_raw = (const unsigned char*)d_in[4];
  const float* Wq = (const float*)d_in[6];
  const float* Wk = (const float*)d_in[7];
  const float* Wv = (const float*)d_in[8];
  const float* Wi = (const float*)d_in[9];
  const float* Wo = (const float*)d_in[10];
  float* out0 = (float*)d_out;                  // (B,L,E)
  float* out1 = out0 + 16777216;                // (B,H,L,G)

  // ---- workspace map (MiB); ws_size = 512 MiB, base layout as r12/r14 ----
  char* ws = (char*)d_ws;
  u16* WoT_hi = (u16*)(ws + 0);
  float* msm_q = (float*)(ws + (2L<<20));
  float* mss_q = (float*)(ws + (2L<<20) + 262144);
  float* msm_g = (float*)(ws + (3L<<20));
  float* mss_g = (float*)(ws + (3L<<20) + 262144);
  u16* WqT_hi = (u16*)(ws + (4L<<20));
  unsigned char* mask_ws = (unsigned char*)(ws + (6L<<20));
  u16* WkT_hi = (u16*)(ws + (8L<<20));
  u16* WvT_hi = (u16*)(ws + (12L<<20));
  u16* gqs_hi = (u16*)(ws + (16L<<20));
  u16* gqs_lo = (u16*)(ws + (17L<<20));
  u16* WiT_hi = (u16*)(ws + (18L<<20));
  u16* qp_hi  = (u16*)(ws + (20L<<20));
  u16* gsc_hi = (u16*)(ws + (20L<<20));
  u16* gsc_lo = (u16*)(ws + (52L<<20));
  u16* qs_hi  = (u16*)(ws + (84L<<20));
  u16* qs_lo  = (u16*)(ws + (116L<<20));
  u16* vs_hi  = (u16*)(ws + (148L<<20));
  u16* vs_lo  = (u16*)(ws + (180L<<20));
  u16* ips_hi = (u16*)(ws + (212L<<20));
  u16* ips_lo = (u16*)(ws + (244L<<20));
  u16* kk_hi  = (u16*)(ws + (212L<<20));
  u16* kk_lo  = (u16*)(ws + (244L<<20));
  u16* gk_hi  = (u16*)(ws + (212L<<20));
  u16* gk_lo  = (u16*)(ws + (213L<<20));
  u16* gv_hi  = (u16*)(ws + (214L<<20));
  u16* gv_lo  = (u16*)(ws + (215L<<20));
  u16* attn_hi = (u16*)(ws + (244L<<20));
  // fresh region [276, 512) MiB: KC=8 split-K partials (16 MiB each)
  float* partg = (float*)(ws + (280L<<20));     // flash_q partials (dead after combine1)
  float* part1 = (float*)(ws + (280L<<20));     // flash_dual P1 (reuses partg space)
  float* part2 = (float*)(ws + (300L<<20));     // flash_dual P2

  const dim3 blk(256);
  const float scale = 0.125f;   // 1/sqrt(64)

  // 0) mask + weights + query conversion
  mask_norm<<<1, blk, 0, stream>>>(mask_raw, mask_ws, 16384);
  transpose_hi5<<<dim3(16,16,5), blk, 0, stream>>>(Wq, Wk, Wv, Wi, Wo,
      WqT_hi, WkT_hi, WvT_hi, WiT_hi, WoT_hi);
  conv_hi<<<8192, blk, 0, stream>>>(query, qp_hi, 2097152);

  // 1) PAIR1: {qs-proj | ips} merged (both read qp; planes out), TM=128
  {
    PArg g0 = { qp_hi,  WqT_hi, qs_hi,  qs_lo,  0L, 0L,
                1024, 1024, 1024, 8, 128 };
    PArg g1 = { WiT_hi, qp_hi,  ips_hi, ips_lo, 2097152L, 2097152L,
                1024, 1024, 2048, 16, 8 };
    gemm_pair<128,1><<<2048, blk, 0, stream>>>(g0, g1, 1024, 1024);
  }

  // 2) MERGED: {kk-proj | vs-proj} (A from fp32 key/value) + flash_q (KC=8)
  {
    PArg g0 = { key,   WkT_hi, kk_hi, kk_lo, 0L, 0L, 1024, 1024, 1024, 8, 128 };
    PArg g1 = { value, WvT_hi, vs_hi, vs_lo, 0L, 0L, 1024, 1024, 1024, 8, 128 };
    pair_flash<<<3072, blk, 37632, stream>>>(g0, g1,
        ips_hi, ips_lo, qs_hi, qs_lo, partg, msm_q, mss_q, 1024);
  }
  flash_combine<1,8><<<128, blk, 0, stream>>>(
      partg, nullptr, msm_q, mss_q, gqs_hi, gqs_lo, nullptr, nullptr, 128);

  // 3) g_scores (2-term A) -> planes; mask+scale in epilogue
  gemm_g<64,2,1,1,0><<<dim3(16,1,128), blk, 0, stream>>>(
      gqs_hi, gqs_lo, kk_hi, gsc_hi, gsc_lo, mask_ws,
      64, 64,1024,2048, 65536L,4096L, 2097152L,64L, 2097152L,131072L, 16, 2048, scale);

  // 4) gk/gv = softmax(g_scores) @ {kk,vs}  (fused dual flash, KC=8)
  flash_agg<2><<<dim3(8,128), blk, 0, stream>>>(
      gsc_hi, gsc_lo, kk_hi, kk_lo, vs_hi, vs_lo,
      part1, part2, msm_g, mss_g,
      2048, 8, 2048, 1024, 2097152L, 131072L, 2097152L, 64L, 16, 128);
  flash_combine<2,8><<<128, blk, 0, stream>>>(
      part1, part2, msm_g, mss_g, gk_hi, gk_lo, gv_hi, gv_lo, 128);

  // 5) stage 2 (MFMA): l_attn (out1) + attn hi plane
  stage2_mfma<<<dim3(16,128), blk, 0, stream>>>(qs_hi, qs_lo, gk_hi, gk_lo,
      gv_hi, gv_lo, out1, attn_hi, scale);

  // 6) out0 = attn @ Wo (TM=128, 1-term, swizzled)
  gemm_g<128,1,0,0,1><<<dim3(8,128,1), blk, 0, stream>>>(
      attn_hi, nullptr, WoT_hi, out0, nullptr, nullptr,
      1024, 1024,1024,1024, 0,0, 0,0, 0,0, 1, 2048, 1.f);

  (void)in_sizes; (void)n_in; (void)out_size; (void)ws_size;
}